// Round 11
// baseline (70.316 us; speedup 1.0000x reference)
//
#include <hip/hip_runtime.h>
#include <hip/hip_bf16.h>
#include <math.h>

#define NBATCH 8
#define NL 128
#define IND 512
#define DEPN 45
#define DEPD 16
#define WCOLS 528          // IN_DIM + DEP_DIM
#define NP 1152            // extended width (U|HT|D1|D2|pad)
#define C_U 0
#define C_HT 512
#define C_D1 1024
#define C_D2 1069
#define C_PAD 1114

typedef __attribute__((ext_vector_type(8))) short bf16x8;
typedef __attribute__((ext_vector_type(4))) float f32x4;

__device__ inline ushort f2bf(float x) {
    __hip_bfloat16 b = __float2bfloat16(x);
    return *reinterpret_cast<ushort*>(&b);
}
__device__ inline float bf2f(ushort u) {
    __hip_bfloat16 b;
    *reinterpret_cast<ushort*>(&b) = u;
    return __bfloat162float(b);
}

// ================= k_prep =================
// [0,64):    A_hi/A_lo = bf16-split of h*wpos (16 rows); blk0: bias_ext HT=bg
// [64,96):   B rows C_HT+o = split of Wg (16 rows each)
// [96,98):   zero B pad rows 1114..1151 (19 each)
// [98,226):  W1hT/W2hT transpose-splits (64x64 LDS tiles; 64 tiles per matrix)
// [226,586): Z rows C_D1/C_D2 + D-bias (recompute Y from emb)
// [586,590): U-bias v[d] = W2h^T b1 + W1h^T b2 (128 d's each); blk586: b1.b2
__global__ __launch_bounds__(256) void k_prep(
    const float* __restrict__ h, const unsigned char* __restrict__ mask,
    const float* __restrict__ emb,
    const float* __restrict__ W1, const float* __restrict__ W2,
    const float* __restrict__ Wg,
    const float* __restrict__ b1, const float* __restrict__ b2,
    const float* __restrict__ bg,
    ushort* __restrict__ A_hi, ushort* __restrict__ A_lo,
    ushort* __restrict__ B_hi, ushort* __restrict__ B_lo,
    ushort* __restrict__ W1T_hi, ushort* __restrict__ W1T_lo,
    ushort* __restrict__ W2T_hi, ushort* __restrict__ W2T_lo,
    float* __restrict__ bias_ext, float* __restrict__ c0const) {
    int bid = blockIdx.x;
    int tid = threadIdx.x;

    if (bid < 64) {
        int rb = bid * 16;
        int b = rb >> 7;
        __shared__ int sflag, smin, smax;
        __shared__ float w16[16];
        if (tid == 0) { sflag = 0; smin = NL; smax = -1; }
        __syncthreads();
        const int* mi = (const int*)mask;
        if (tid < 128) {
            int v0 = mi[tid], v1 = mi[tid + 128];
            if ((unsigned)v0 > 1u || (unsigned)v1 > 1u) atomicOr(&sflag, 1);
        }
        __syncthreads();
        if (tid < 128) {
            int mval = sflag ? (int)mask[b * NL + tid] : mi[b * NL + tid];
            if (mval) { atomicMin(&smin, tid); atomicMax(&smax, tid); }
        }
        __syncthreads();
        if (tid < 16) {
            int any = (smax >= 0);
            int s = any ? smin : 0;
            int e = any ? smax : (NL - 1);
            int i = (rb & 127) + tid;
            const float invL = 1.0f / (float)NL;
            float w;
            if (i < s)      w = 1.0f - (float)(s - i) * invL;
            else if (i > e) w = 1.0f - (float)(i - e) * invL;
            else            w = 0.0f;
            int mval = sflag ? (int)mask[b * NL + i] : mi[b * NL + i];
            if (mval) w = 0.0f;
            w16[tid] = w;
        }
        __syncthreads();
        for (int idx = tid; idx < 16 * 128; idx += 256) {
            int r = idx >> 7, dc = (idx & 127) << 2;
            float4 hv = *(const float4*)&h[(size_t)(rb + r) * IND + dc];
            float wv = w16[r];
            hv.x *= wv; hv.y *= wv; hv.z *= wv; hv.w *= wv;
            ushort4 hi4, lo4;
            hi4.x = f2bf(hv.x); hi4.y = f2bf(hv.y); hi4.z = f2bf(hv.z); hi4.w = f2bf(hv.w);
            lo4.x = f2bf(hv.x - bf2f(hi4.x));
            lo4.y = f2bf(hv.y - bf2f(hi4.y));
            lo4.z = f2bf(hv.z - bf2f(hi4.z));
            lo4.w = f2bf(hv.w - bf2f(hi4.w));
            *(ushort4*)&A_hi[(size_t)(rb + r) * IND + dc] = hi4;
            *(ushort4*)&A_lo[(size_t)(rb + r) * IND + dc] = lo4;
        }
        if (bid == 0) {
            for (int i = tid; i < 512; i += 256) bias_ext[C_HT + i] = bg[i];
        }
    } else if (bid < 96) {
        // ---- B rows C_HT..C_HT+512 = Wg split ----
        int nb = (bid - 64) * 16;
        for (int idx = tid; idx < 16 * 128; idx += 256) {
            int r = idx >> 7, dc = (idx & 127) << 2;
            int o = nb + r;
            float4 wv = *(const float4*)(Wg + (size_t)o * IND + dc);
            ushort4 hi4, lo4;
            hi4.x = f2bf(wv.x); hi4.y = f2bf(wv.y); hi4.z = f2bf(wv.z); hi4.w = f2bf(wv.w);
            lo4.x = f2bf(wv.x - bf2f(hi4.x));
            lo4.y = f2bf(wv.y - bf2f(hi4.y));
            lo4.z = f2bf(wv.z - bf2f(hi4.z));
            lo4.w = f2bf(wv.w - bf2f(hi4.w));
            *(ushort4*)&B_hi[(size_t)(C_HT + o) * IND + dc] = hi4;
            *(ushort4*)&B_lo[(size_t)(C_HT + o) * IND + dc] = lo4;
        }
    } else if (bid < 98) {
        int nb = C_PAD + (bid - 96) * 19;
        ushort4 z4 = {0, 0, 0, 0};
        for (int idx = tid; idx < 19 * 128; idx += 256) {
            int r = idx >> 7, dc = (idx & 127) << 2;
            *(ushort4*)&B_hi[(size_t)(nb + r) * IND + dc] = z4;
            *(ushort4*)&B_lo[(size_t)(nb + r) * IND + dc] = z4;
        }
    } else if (bid < 226) {
        // ---- transpose-split W1h / W2h -> WT[d][o] bf16 hi/lo ----
        int blk2 = bid - 98;
        int mt = blk2 >> 6;
        int t = blk2 & 63;
        int orow = (t >> 3) * 64;
        int dcol = (t & 7) * 64;
        const float* W = mt ? W2 : W1;
        ushort* Th = mt ? W2T_hi : W1T_hi;
        ushort* Tl = mt ? W2T_lo : W1T_lo;
        __shared__ float tl[64][65];
        int tx = tid & 63, ty = tid >> 6;
#pragma unroll
        for (int r = 0; r < 64; r += 4)
            tl[ty + r][tx] = W[(size_t)(orow + ty + r) * WCOLS + dcol + tx];
        __syncthreads();
#pragma unroll
        for (int r = 0; r < 64; r += 4) {
            float v = tl[tx][ty + r];
            ushort hi = f2bf(v);
            size_t idx = (size_t)(dcol + ty + r) * IND + orow + tx;
            Th[idx] = hi;
            Tl[idx] = f2bf(v - bf2f(hi));
        }
    } else if (bid < 586) {
        // ---- Z rows + D-bias ----
        int zi = bid - 226;
        int t = zi % 45;
        int m = (zi / 45) & 1;
        int dq = zi / 90;
        __shared__ float es[DEPD];
        __shared__ float ys[512];
        __shared__ float y1s[512];
        __shared__ float part[256];
        if (tid < DEPD) es[tid] = emb[t * DEPD + tid];
        __syncthreads();
        const float* Wdep = (m == 0) ? W2 : W1;
        for (int o = tid; o < 512; o += 256) {
            float s = 0.f;
#pragma unroll
            for (int e = 0; e < DEPD; e++) s += es[e] * Wdep[o * WCOLS + IND + e];
            ys[o] = s;
        }
        if (m == 0 && dq == 0) {
            for (int o = tid; o < 512; o += 256) {
                float s = 0.f;
#pragma unroll
                for (int e = 0; e < DEPD; e++) s += es[e] * W1[o * WCOLS + IND + e];
                y1s[o] = s;
            }
        }
        __syncthreads();
        int dloc = tid & 127, half = tid >> 7;
        const float* Wsrc = (m == 0) ? W1 : W2;
        int d = dq * 128 + dloc;
        int obase = half * 256;
        float s = 0.f;
#pragma unroll 16
        for (int oo = 0; oo < 256; oo++)
            s += Wsrc[(size_t)(obase + oo) * WCOLS + d] * ys[obase + oo];
        part[tid] = s;
        __syncthreads();
        int row = ((m == 0) ? C_D1 : C_D2) + t;
        if (half == 0) {
            float tot = part[dloc] + part[128 + dloc];
            ushort hi = f2bf(tot);
            B_hi[(size_t)row * IND + d] = hi;
            B_lo[(size_t)row * IND + d] = f2bf(tot - bf2f(hi));
        }
        if (dq == 0 && tid < 64) {
            const float* bb = (m == 0) ? b1 : b2;
            float sb = 0.f;
#pragma unroll
            for (int k = 0; k < 8; k++) sb += bb[tid + k * 64] * ys[tid + k * 64];
            if (m == 0) {
#pragma unroll
                for (int k = 0; k < 8; k++) sb += y1s[tid + k * 64] * ys[tid + k * 64];
            }
            for (int off = 32; off; off >>= 1) sb += __shfl_down(sb, off, 64);
            if (tid == 0) bias_ext[row] = sb;
        }
    } else {
        // ---- v (U bias) + b1.b2 ----
        int dchunk = bid - 586;
        int dloc = tid & 127, half = tid >> 7;
        __shared__ float part[256];
        int d = dchunk * 128 + dloc;
        int obase = half * 256;
        float s = 0.f;
#pragma unroll 16
        for (int oo = 0; oo < 256; oo++) {
            int o = obase + oo;
            s += W2[(size_t)o * WCOLS + d] * b1[o] + W1[(size_t)o * WCOLS + d] * b2[o];
        }
        part[tid] = s;
        __syncthreads();
        if (half == 0) bias_ext[C_U + d] = part[dloc] + part[128 + dloc];
        if (dchunk == 0 && tid < 64) {
            float sb = 0.f;
#pragma unroll
            for (int k = 0; k < 8; k++) sb += b1[tid + k * 64] * b2[tid + k * 64];
            for (int off = 32; off; off >>= 1) sb += __shfl_down(sb, off, 64);
            if (tid == 0) c0const[0] = sb;
        }
    }
}

// ===== shared GEMM macros (A[m][k], B[n][k], hi/lo 3-term) =====
#define LOADSET(P, KS) \
    P##a0h = *(const bf16x8*)(A_hi + (size_t)rA0 * IND + (KS) * 32 + kg8); \
    P##a0l = *(const bf16x8*)(A_lo + (size_t)rA0 * IND + (KS) * 32 + kg8); \
    P##a1h = *(const bf16x8*)(A_hi + (size_t)rA1 * IND + (KS) * 32 + kg8); \
    P##a1l = *(const bf16x8*)(A_lo + (size_t)rA1 * IND + (KS) * 32 + kg8); \
    P##b0h = *(const bf16x8*)(B_hi + (size_t)cB0 * IND + (KS) * 32 + kg8); \
    P##b0l = *(const bf16x8*)(B_lo + (size_t)cB0 * IND + (KS) * 32 + kg8); \
    P##b1h = *(const bf16x8*)(B_hi + (size_t)cB1 * IND + (KS) * 32 + kg8); \
    P##b1l = *(const bf16x8*)(B_lo + (size_t)cB1 * IND + (KS) * 32 + kg8);

#define MFMASET(P) \
    acc00 = __builtin_amdgcn_mfma_f32_16x16x32_bf16(P##a0h, P##b0h, acc00, 0, 0, 0); \
    acc00 = __builtin_amdgcn_mfma_f32_16x16x32_bf16(P##a0h, P##b0l, acc00, 0, 0, 0); \
    acc00 = __builtin_amdgcn_mfma_f32_16x16x32_bf16(P##a0l, P##b0h, acc00, 0, 0, 0); \
    acc01 = __builtin_amdgcn_mfma_f32_16x16x32_bf16(P##a0h, P##b1h, acc01, 0, 0, 0); \
    acc01 = __builtin_amdgcn_mfma_f32_16x16x32_bf16(P##a0h, P##b1l, acc01, 0, 0, 0); \
    acc01 = __builtin_amdgcn_mfma_f32_16x16x32_bf16(P##a0l, P##b1h, acc01, 0, 0, 0); \
    acc10 = __builtin_amdgcn_mfma_f32_16x16x32_bf16(P##a1h, P##b0h, acc10, 0, 0, 0); \
    acc10 = __builtin_amdgcn_mfma_f32_16x16x32_bf16(P##a1h, P##b0l, acc10, 0, 0, 0); \
    acc10 = __builtin_amdgcn_mfma_f32_16x16x32_bf16(P##a1l, P##b0h, acc10, 0, 0, 0); \
    acc11 = __builtin_amdgcn_mfma_f32_16x16x32_bf16(P##a1h, P##b1h, acc11, 0, 0, 0); \
    acc11 = __builtin_amdgcn_mfma_f32_16x16x32_bf16(P##a1h, P##b1l, acc11, 0, 0, 0); \
    acc11 = __builtin_amdgcn_mfma_f32_16x16x32_bf16(P##a1l, P##b1h, acc11, 0, 0, 0);

#define GEMM_BODY \
    f32x4 acc00 = {0.f, 0.f, 0.f, 0.f}; \
    f32x4 acc01 = acc00, acc10 = acc00, acc11 = acc00; \
    bf16x8 pa0h, pa0l, pa1h, pa1l, pb0h, pb0l, pb1h, pb1l; \
    bf16x8 qa0h, qa0l, qa1h, qa1l, qb0h, qb0l, qb1h, qb1l; \
    LOADSET(p, 0) \
    _Pragma("unroll") \
    for (int ks = 0; ks < 16; ks += 2) { \
        LOADSET(q, ks + 1) \
        MFMASET(p) \
        int kn = (ks + 2) & 15; \
        LOADSET(p, kn) \
        MFMASET(q) \
    }

// ================= kG: G = W1h^T W2h (512x512), split output into B rows =================
__global__ __launch_bounds__(128) void kG_gemm(
    const ushort* __restrict__ A_hi, const ushort* __restrict__ A_lo,   // W1T splits
    const ushort* __restrict__ B_hi, const ushort* __restrict__ B_lo,   // W2T splits
    ushort* __restrict__ Gdst_hi, ushort* __restrict__ Gdst_lo) {       // B rows C_U+e
    int tid = threadIdx.x;
    int wid = tid >> 6, lane = tid & 63;
    int lrow = lane & 15, kg8 = (lane >> 4) << 3;
    int mbase = blockIdx.x * 64 + wid * 32;
    int nbase = blockIdx.y * 32;
    int rA0 = mbase + lrow, rA1 = rA0 + 16;
    int cB0 = nbase + lrow, cB1 = cB0 + 16;

    GEMM_BODY

    int r0 = (lane >> 4) << 2;
    int col0 = nbase + lrow;
    int col1 = col0 + 16;
#pragma unroll
    for (int r = 0; r < 4; ++r) {
        int e0 = mbase + r0 + r;
        int e1 = e0 + 16;
        float v;
        ushort hi;
#define GSTORE(EE, CC, ACC) \
        v = ACC[r]; hi = f2bf(v); \
        Gdst_hi[(size_t)(C_U + (EE)) * IND + (CC)] = hi; \
        Gdst_lo[(size_t)(C_U + (EE)) * IND + (CC)] = f2bf(v - bf2f(hi));
        GSTORE(e0, col0, acc00)
        GSTORE(e0, col1, acc01)
        GSTORE(e1, col0, acc10)
        GSTORE(e1, col1, acc11)
#undef GSTORE
    }
}

// ================= k3: Pout = A @ B^T + bias_ext =================
// NP=1152; grid (16, 36); HT cols -> transposed bf16 hi/lo HTt[b][o][j]
__global__ __launch_bounds__(128) void k3_gemm(
    const ushort* __restrict__ A_hi, const ushort* __restrict__ A_lo,
    const ushort* __restrict__ B_hi, const ushort* __restrict__ B_lo,
    const float* __restrict__ bias_ext, float* __restrict__ Pout,
    ushort* __restrict__ HTt_hi, ushort* __restrict__ HTt_lo) {
    int tid = threadIdx.x;
    int wid = tid >> 6, lane = tid & 63;
    int lrow = lane & 15, kg8 = (lane >> 4) << 3;
    int mbase = blockIdx.x * 64 + wid * 32;
    int nbase = blockIdx.y * 32;
    int rA0 = mbase + lrow, rA1 = rA0 + 16;
    int cB0 = nbase + lrow, cB1 = cB0 + 16;

    GEMM_BODY

    int r0 = (lane >> 4) << 2;
    int col0 = nbase + lrow;
    int col1 = col0 + 16;
    float bv0 = bias_ext[col0];
    float bv1 = bias_ext[col1];

    if (nbase >= C_HT && nbase < C_HT + 512) {
        int b = mbase >> 7;
        int o0 = col0 - C_HT, o1 = col1 - C_HT;
        int j0 = (mbase & 127) + r0;
        ushort4 h4, l4;
        float v0f, v1f, v2f, v3f;
#define PACK_STORE(ACC, BV, OO, JJ) \
        v0f = ACC[0] + BV; v1f = ACC[1] + BV; v2f = ACC[2] + BV; v3f = ACC[3] + BV; \
        h4.x = f2bf(v0f); h4.y = f2bf(v1f); h4.z = f2bf(v2f); h4.w = f2bf(v3f); \
        l4.x = f2bf(v0f - bf2f(h4.x)); l4.y = f2bf(v1f - bf2f(h4.y)); \
        l4.z = f2bf(v2f - bf2f(h4.z)); l4.w = f2bf(v3f - bf2f(h4.w)); \
        *(ushort4*)&HTt_hi[((size_t)(b * 512 + (OO))) * 128 + (JJ)] = h4; \
        *(ushort4*)&HTt_lo[((size_t)(b * 512 + (OO))) * 128 + (JJ)] = l4;
        PACK_STORE(acc00, bv0, o0, j0)
        PACK_STORE(acc01, bv1, o1, j0)
        PACK_STORE(acc10, bv0, o0, j0 + 16)
        PACK_STORE(acc11, bv1, o1, j0 + 16)
#undef PACK_STORE
    } else {
#pragma unroll
        for (int r = 0; r < 4; ++r) {
            int row0 = mbase + r0 + r;
            int row1 = row0 + 16;
            Pout[(size_t)row0 * NP + col0] = acc00[r] + bv0;
            Pout[(size_t)row0 * NP + col1] = acc01[r] + bv1;
            Pout[(size_t)row1 * NP + col0] = acc10[r] + bv0;
            Pout[(size_t)row1 * NP + col1] = acc11[r] + bv1;
        }
    }
}

// ================= k5: c0 from U, softmax, S@HT (MFMA), relu =================
// grid 64 = 8 b x 4 rowgroups x 2 o-chunks.
__global__ __launch_bounds__(256) void k5_out(
    const float* __restrict__ P, const int* __restrict__ dep,
    const ushort* __restrict__ A_hi, const ushort* __restrict__ A_lo,
    const ushort* __restrict__ HTt_hi, const ushort* __restrict__ HTt_lo,
    const float* __restrict__ bias, const float* __restrict__ c0const,
    float* __restrict__ out) {
    int blk = blockIdx.x;
    int oc = blk & 1, rg = (blk >> 1) & 3, b = blk >> 3;
    int i0 = b * 128 + rg * 32;
    int tid = threadIdx.x;
    __shared__ float c0s[32];
    __shared__ float combs[32][48];
    __shared__ ushort Sh[32][128];
    __shared__ ushort Sl[32][128];
    __shared__ float invs[32];

    float c0c = c0const[0];
    // phase A: c0[row] = U_row . h_row + b1.b2  (8 threads/row)
    {
        int row = tid >> 3, ch = (tid & 7) * 64;
        const float* up = P + (size_t)(i0 + row) * NP + C_U + ch;
        const ushort* ahp = A_hi + (size_t)(i0 + row) * IND + ch;
        const ushort* alp = A_lo + (size_t)(i0 + row) * IND + ch;
        float s = 0.f;
#pragma unroll
        for (int k = 0; k < 16; k++) {
            float4 u = *(const float4*)(up + k * 4);
            ushort4 hh = *(const ushort4*)(ahp + k * 4);
            ushort4 ll = *(const ushort4*)(alp + k * 4);
            s += u.x * (bf2f(hh.x) + bf2f(ll.x));
            s += u.y * (bf2f(hh.y) + bf2f(ll.y));
            s += u.z * (bf2f(hh.z) + bf2f(ll.z));
            s += u.w * (bf2f(hh.w) + bf2f(ll.w));
        }
        s += __shfl_xor(s, 1, 64); s += __shfl_xor(s, 2, 64); s += __shfl_xor(s, 4, 64);
        if ((tid & 7) == 0) c0s[row] = s + c0c;
    }
    // phase B
    for (int idx = tid; idx < 32 * 45; idx += 256) {
        int r = idx / 45, t = idx - r * 45;
        const float* Prow = P + (size_t)(i0 + r) * NP;
        combs[r][t] = Prow[C_D1 + t] + Prow[C_D2 + t];
    }
    __syncthreads();

    // phase C: stable scores
    {
        int row = tid >> 3, j0 = (tid & 7) * 16;
        const int* dp = dep + (size_t)(i0 + row) * NL + j0;
        float vals[16]; int valid[16];
        float M = -3.0e38f;
#pragma unroll
        for (int jj = 0; jj < 16; jj++) {
            int tt = dp[jj];
            valid[jj] = (tt != 0);
            vals[jj] = combs[row][tt];
            if (valid[jj]) M = fmaxf(M, vals[jj]);
        }
        M = fmaxf(M, __shfl_xor(M, 1, 64));
        M = fmaxf(M, __shfl_xor(M, 2, 64));
        M = fmaxf(M, __shfl_xor(M, 4, 64));
        float sum = 0.f;
#pragma unroll
        for (int jj = 0; jj < 16; jj++) {
            float a = valid[jj] ? expf(vals[jj] - M) : 0.f;
            sum += a;
            ushort hi = f2bf(a);
            Sh[row][j0 + jj] = hi;
            Sl[row][j0 + jj] = f2bf(a - bf2f(hi));
        }
        sum += __shfl_xor(sum, 1, 64);
        sum += __shfl_xor(sum, 2, 64);
        sum += __shfl_xor(sum, 4, 64);
        if ((tid & 7) == 0) {
            float corr = 1e-6f * expf(-(c0s[row] + M));
            invs[row] = 1.0f / (sum + corr);
        }
    }
    __syncthreads();

    // phase D: 256 o-cols (this oc), 4 waves x 64 o
    int wid = tid >> 6, lane = tid & 63;
    int lrow = lane & 15, kg8 = (lane >> 4) << 3;
    int obase = oc * 256 + wid * 64;
    f32x4 z = {0.f, 0.f, 0.f, 0.f};
    f32x4 acc0[4] = {z, z, z, z};
    f32x4 acc1[4] = {z, z, z, z};
#pragma unroll
    for (int ks = 0; ks < 4; ks++) {
        bf16x8 a0h = *(const bf16x8*)&Sh[lrow][ks * 32 + kg8];
        bf16x8 a0l = *(const bf16x8*)&Sl[lrow][ks * 32 + kg8];
        bf16x8 a1h = *(const bf16x8*)&Sh[16 + lrow][ks * 32 + kg8];
        bf16x8 a1l = *(const bf16x8*)&Sl[16 + lrow][ks * 32 + kg8];
#pragma unroll
        for (int nf = 0; nf < 4; nf++) {
            int o = obase + nf * 16 + lrow;
            size_t base = ((size_t)(b * 512 + o)) * 128 + ks * 32 + kg8;
            bf16x8 bh = *(const bf16x8*)(HTt_hi + base);
            bf16x8 bl = *(const bf16x8*)(HTt_lo + base);
            acc0[nf] = __builtin_amdgcn_mfma_f32_16x16x32_bf16(a0h, bh, acc0[nf], 0, 0, 0);
            acc0[nf] = __builtin_amdgcn_mfma_f32_16x16x32_bf16(a0h, bl, acc0[nf], 0, 0, 0);
            acc0[nf] = __builtin_amdgcn_mfma_f32_16x16x32_bf16(a0l, bh, acc0[nf], 0, 0, 0);
            acc1[nf] = __builtin_amdgcn_mfma_f32_16x16x32_bf16(a1h, bh, acc1[nf], 0, 0, 0);
            acc1[nf] = __builtin_amdgcn_mfma_f32_16x16x32_bf16(a1h, bl, acc1[nf], 0, 0, 0);
            acc1[nf] = __builtin_amdgcn_mfma_f32_16x16x32_bf16(a1l, bh, acc1[nf], 0, 0, 0);
        }
    }

    int r0 = (lane >> 4) << 2;
#pragma unroll
    for (int nf = 0; nf < 4; nf++) {
        int o = obase + nf * 16 + lrow;
        float bv = bias[o];
#pragma unroll
        for (int r = 0; r < 4; r++) {
            int i0r = r0 + r;
            float v0 = acc0[nf][r] * invs[i0r] + bv;
            float v1 = acc1[nf][r] * invs[16 + i0r] + bv;
            out[(size_t)(i0 + i0r) * 512 + o] = fmaxf(v0, 0.f);
            out[(size_t)(i0 + 16 + i0r) * 512 + o] = fmaxf(v1, 0.f);
        }
    }
}

extern "C" void kernel_launch(void* const* d_in, const int* in_sizes, int n_in,
                              void* d_out, int out_size, void* d_ws, size_t ws_size,
                              hipStream_t stream) {
    const float* h    = (const float*)d_in[0];
    const int* dep    = (const int*)d_in[1];
    const unsigned char* mask = (const unsigned char*)d_in[2];
    const float* emb  = (const float*)d_in[3];
    const float* W1   = (const float*)d_in[4];
    const float* b1   = (const float*)d_in[5];
    const float* W2   = (const float*)d_in[6];
    const float* b2   = (const float*)d_in[7];
    const float* Wg   = (const float*)d_in[8];
    const float* bg   = (const float*)d_in[9];
    const float* bias = (const float*)d_in[10];
    float* out = (float*)d_out;

    char* p = (char*)d_ws;
    ushort* A_hi = (ushort*)p;   p += (size_t)1024 * 512 * 2;
    ushort* A_lo = (ushort*)p;   p += (size_t)1024 * 512 * 2;
    ushort* B_hi = (ushort*)p;   p += (size_t)NP * 512 * 2;
    ushort* B_lo = (ushort*)p;   p += (size_t)NP * 512 * 2;
    ushort* W1T_hi = (ushort*)p; p += (size_t)512 * 512 * 2;
    ushort* W1T_lo = (ushort*)p; p += (size_t)512 * 512 * 2;
    ushort* W2T_hi = (ushort*)p; p += (size_t)512 * 512 * 2;
    ushort* W2T_lo = (ushort*)p; p += (size_t)512 * 512 * 2;
    ushort* HTt_hi = (ushort*)p; p += (size_t)8 * 512 * 128 * 2;
    ushort* HTt_lo = (ushort*)p; p += (size_t)8 * 512 * 128 * 2;
    float* bias_ext = (float*)p; p += NP * 4;
    float* c0const = (float*)p;  p += 64 * 4;
    float* Pout = (float*)p;     // 1024*1152*4 = 4.7 MB

    k_prep<<<590, 256, 0, stream>>>(h, mask, emb, W1, W2, Wg, b1, b2, bg,
                                    A_hi, A_lo, B_hi, B_lo,
                                    W1T_hi, W1T_lo, W2T_hi, W2T_lo,
                                    bias_ext, c0const);
    dim3 gG(8, 16);
    kG_gemm<<<gG, 128, 0, stream>>>(W1T_hi, W1T_lo, W2T_hi, W2T_lo, B_hi, B_lo);
    dim3 g3(16, 36);
    k3_gemm<<<g3, 128, 0, stream>>>(A_hi, A_lo, B_hi, B_lo, bias_ext, Pout,
                                    HTt_hi, HTt_lo);
    k5_out<<<64, 256, 0, stream>>>(Pout, dep, A_hi, A_lo, HTt_hi, HTt_lo,
                                   bias, c0const, out);
}

// Round 12
// 57.732 us; speedup vs baseline: 1.2180x; 1.2180x over previous
//
#include <hip/hip_runtime.h>
#include <hip/hip_bf16.h>
#include <math.h>

#define NBATCH 8
#define NL 128
#define IND 512
#define DEPN 45
#define DEPD 16
#define WCOLS 528          // IN_DIM + DEP_DIM
#define NP 1664            // extended width (P1|P2|HT|D1|D2|pad)
#define C_P1 0
#define C_P2 512
#define C_HT 1024
#define C_D1 1536
#define C_D2 1581
#define C_PAD 1626

typedef __attribute__((ext_vector_type(8))) short bf16x8;
typedef __attribute__((ext_vector_type(4))) float f32x4;

__device__ inline ushort f2bf(float x) {
    __hip_bfloat16 b = __float2bfloat16(x);
    return *reinterpret_cast<ushort*>(&b);
}
__device__ inline float bf2f(ushort u) {
    __hip_bfloat16 b;
    *reinterpret_cast<ushort*>(&b) = u;
    return __bfloat162float(b);
}

// ================= k_prep (merged) =================
// [0,64):    A_hi/A_lo = bf16-split of h*wpos (16 rows); blk0: bias_ext base/pad
// [64,160):  B rows 0..1535 = split of W1h|W2h|Wg (16 rows each)
// [160,162): zero B pad rows 1626..1663 (19 each)
// [162,522): Z rows + D-bias (t,m,dq decomposition; Y recomputed from emb)
__global__ __launch_bounds__(256) void k_prep(
    const float* __restrict__ h, const unsigned char* __restrict__ mask,
    const float* __restrict__ emb,
    const float* __restrict__ W1, const float* __restrict__ W2,
    const float* __restrict__ Wg,
    const float* __restrict__ b1, const float* __restrict__ b2,
    const float* __restrict__ bg,
    ushort* __restrict__ A_hi, ushort* __restrict__ A_lo,
    ushort* __restrict__ B_hi, ushort* __restrict__ B_lo,
    float* __restrict__ bias_ext) {
    int bid = blockIdx.x;
    int tid = threadIdx.x;

    if (bid < 64) {
        int rb = bid * 16;
        int b = rb >> 7;
        __shared__ int sflag, smin, smax;
        __shared__ float w16[16];
        if (tid == 0) { sflag = 0; smin = NL; smax = -1; }
        __syncthreads();
        const int* mi = (const int*)mask;
        if (tid < 128) {
            int v0 = mi[tid], v1 = mi[tid + 128];
            if ((unsigned)v0 > 1u || (unsigned)v1 > 1u) atomicOr(&sflag, 1);
        }
        __syncthreads();
        if (tid < 128) {
            int mval = sflag ? (int)mask[b * NL + tid] : mi[b * NL + tid];
            if (mval) { atomicMin(&smin, tid); atomicMax(&smax, tid); }
        }
        __syncthreads();
        if (tid < 16) {
            int any = (smax >= 0);
            int s = any ? smin : 0;
            int e = any ? smax : (NL - 1);
            int i = (rb & 127) + tid;
            const float invL = 1.0f / (float)NL;
            float w;
            if (i < s)      w = 1.0f - (float)(s - i) * invL;
            else if (i > e) w = 1.0f - (float)(i - e) * invL;
            else            w = 0.0f;
            int mval = sflag ? (int)mask[b * NL + i] : mi[b * NL + i];
            if (mval) w = 0.0f;
            w16[tid] = w;
        }
        __syncthreads();
        for (int idx = tid; idx < 16 * 128; idx += 256) {
            int r = idx >> 7, dc = (idx & 127) << 2;
            float4 hv = *(const float4*)&h[(size_t)(rb + r) * IND + dc];
            float wv = w16[r];
            hv.x *= wv; hv.y *= wv; hv.z *= wv; hv.w *= wv;
            ushort4 hi4, lo4;
            hi4.x = f2bf(hv.x); hi4.y = f2bf(hv.y); hi4.z = f2bf(hv.z); hi4.w = f2bf(hv.w);
            lo4.x = f2bf(hv.x - bf2f(hi4.x));
            lo4.y = f2bf(hv.y - bf2f(hi4.y));
            lo4.z = f2bf(hv.z - bf2f(hi4.z));
            lo4.w = f2bf(hv.w - bf2f(hi4.w));
            *(ushort4*)&A_hi[(size_t)(rb + r) * IND + dc] = hi4;
            *(ushort4*)&A_lo[(size_t)(rb + r) * IND + dc] = lo4;
        }
        if (bid == 0) {
            for (int i = tid; i < 512; i += 256) {
                bias_ext[C_P1 + i] = b1[i];
                bias_ext[C_P2 + i] = b2[i];
                bias_ext[C_HT + i] = bg[i];
            }
            if (tid < NP - C_PAD) bias_ext[C_PAD + tid] = 0.f;
        }
    } else if (bid < 160) {
        int nb = (bid - 64) * 16;
        for (int idx = tid; idx < 16 * 128; idx += 256) {
            int r = idx >> 7, dc = (idx & 127) << 2;
            int n = nb + r;
            const float* src;
            if (n < 512)       src = W1 + (size_t)n * WCOLS + dc;
            else if (n < 1024) src = W2 + (size_t)(n - 512) * WCOLS + dc;
            else               src = Wg + (size_t)(n - 1024) * IND + dc;
            float4 wv = *(const float4*)src;
            ushort4 hi4, lo4;
            hi4.x = f2bf(wv.x); hi4.y = f2bf(wv.y); hi4.z = f2bf(wv.z); hi4.w = f2bf(wv.w);
            lo4.x = f2bf(wv.x - bf2f(hi4.x));
            lo4.y = f2bf(wv.y - bf2f(hi4.y));
            lo4.z = f2bf(wv.z - bf2f(hi4.z));
            lo4.w = f2bf(wv.w - bf2f(hi4.w));
            *(ushort4*)&B_hi[(size_t)n * IND + dc] = hi4;
            *(ushort4*)&B_lo[(size_t)n * IND + dc] = lo4;
        }
    } else if (bid < 162) {
        int nb = 1626 + (bid - 160) * 19;
        ushort4 z4 = {0, 0, 0, 0};
        for (int idx = tid; idx < 19 * 128; idx += 256) {
            int r = idx >> 7, dc = (idx & 127) << 2;
            *(ushort4*)&B_hi[(size_t)(nb + r) * IND + dc] = z4;
            *(ushort4*)&B_lo[(size_t)(nb + r) * IND + dc] = z4;
        }
    } else {
        // ---- Z rows + D-bias ----
        int zi = bid - 162;
        int t = zi % 45;
        int m = (zi / 45) & 1;
        int dq = zi / 90;
        __shared__ float es[DEPD];
        __shared__ float ys[512];
        __shared__ float y1s[512];
        __shared__ float part[256];
        if (tid < DEPD) es[tid] = emb[t * DEPD + tid];
        __syncthreads();
        const float* Wdep = (m == 0) ? W2 : W1;
        for (int o = tid; o < 512; o += 256) {
            float s = 0.f;
#pragma unroll
            for (int e = 0; e < DEPD; e++) s += es[e] * Wdep[o * WCOLS + IND + e];
            ys[o] = s;
        }
        if (m == 0 && dq == 0) {
            for (int o = tid; o < 512; o += 256) {
                float s = 0.f;
#pragma unroll
                for (int e = 0; e < DEPD; e++) s += es[e] * W1[o * WCOLS + IND + e];
                y1s[o] = s;
            }
        }
        __syncthreads();
        int dloc = tid & 127, half = tid >> 7;
        const float* Wsrc = (m == 0) ? W1 : W2;
        int d = dq * 128 + dloc;
        int obase = half * 256;
        float s = 0.f;
#pragma unroll 16
        for (int oo = 0; oo < 256; oo++)
            s += Wsrc[(size_t)(obase + oo) * WCOLS + d] * ys[obase + oo];
        part[tid] = s;
        __syncthreads();
        int row = ((m == 0) ? C_D1 : C_D2) + t;
        if (half == 0) {
            float tot = part[dloc] + part[128 + dloc];
            ushort hi = f2bf(tot);
            B_hi[(size_t)row * IND + d] = hi;
            B_lo[(size_t)row * IND + d] = f2bf(tot - bf2f(hi));
        }
        if (dq == 0 && tid < 64) {
            const float* bb = (m == 0) ? b1 : b2;
            float sb = 0.f;
#pragma unroll
            for (int k = 0; k < 8; k++) sb += bb[tid + k * 64] * ys[tid + k * 64];
            if (m == 0) {
#pragma unroll
                for (int k = 0; k < 8; k++) sb += y1s[tid + k * 64] * ys[tid + k * 64];
            }
            for (int off = 32; off; off >>= 1) sb += __shfl_down(sb, off, 64);
            if (tid == 0) bias_ext[row] = sb;
        }
    }
}

// ================= k3: Pout = A @ B^T + bias_ext  (MFMA, hi/lo bf16) =================
// 128 thr = 2 waves; wave tile 32x32; block tile 64m x 32n; grid (16, 52).
// HT col-blocks write compact bf16 HTb[row][o] (hi only) instead of fp32 Pout.
#define LOADSET(P, KS) \
    P##a0h = *(const bf16x8*)(A_hi + (size_t)rA0 * IND + (KS) * 32 + kg8); \
    P##a0l = *(const bf16x8*)(A_lo + (size_t)rA0 * IND + (KS) * 32 + kg8); \
    P##a1h = *(const bf16x8*)(A_hi + (size_t)rA1 * IND + (KS) * 32 + kg8); \
    P##a1l = *(const bf16x8*)(A_lo + (size_t)rA1 * IND + (KS) * 32 + kg8); \
    P##b0h = *(const bf16x8*)(B_hi + (size_t)cB0 * IND + (KS) * 32 + kg8); \
    P##b0l = *(const bf16x8*)(B_lo + (size_t)cB0 * IND + (KS) * 32 + kg8); \
    P##b1h = *(const bf16x8*)(B_hi + (size_t)cB1 * IND + (KS) * 32 + kg8); \
    P##b1l = *(const bf16x8*)(B_lo + (size_t)cB1 * IND + (KS) * 32 + kg8);

#define MFMASET(P) \
    acc00 = __builtin_amdgcn_mfma_f32_16x16x32_bf16(P##a0h, P##b0h, acc00, 0, 0, 0); \
    acc00 = __builtin_amdgcn_mfma_f32_16x16x32_bf16(P##a0h, P##b0l, acc00, 0, 0, 0); \
    acc00 = __builtin_amdgcn_mfma_f32_16x16x32_bf16(P##a0l, P##b0h, acc00, 0, 0, 0); \
    acc01 = __builtin_amdgcn_mfma_f32_16x16x32_bf16(P##a0h, P##b1h, acc01, 0, 0, 0); \
    acc01 = __builtin_amdgcn_mfma_f32_16x16x32_bf16(P##a0h, P##b1l, acc01, 0, 0, 0); \
    acc01 = __builtin_amdgcn_mfma_f32_16x16x32_bf16(P##a0l, P##b1h, acc01, 0, 0, 0); \
    acc10 = __builtin_amdgcn_mfma_f32_16x16x32_bf16(P##a1h, P##b0h, acc10, 0, 0, 0); \
    acc10 = __builtin_amdgcn_mfma_f32_16x16x32_bf16(P##a1h, P##b0l, acc10, 0, 0, 0); \
    acc10 = __builtin_amdgcn_mfma_f32_16x16x32_bf16(P##a1l, P##b0h, acc10, 0, 0, 0); \
    acc11 = __builtin_amdgcn_mfma_f32_16x16x32_bf16(P##a1h, P##b1h, acc11, 0, 0, 0); \
    acc11 = __builtin_amdgcn_mfma_f32_16x16x32_bf16(P##a1h, P##b1l, acc11, 0, 0, 0); \
    acc11 = __builtin_amdgcn_mfma_f32_16x16x32_bf16(P##a1l, P##b1h, acc11, 0, 0, 0);

__global__ __launch_bounds__(128) void k3_gemm(
    const ushort* __restrict__ A_hi, const ushort* __restrict__ A_lo,
    const ushort* __restrict__ B_hi, const ushort* __restrict__ B_lo,
    const float* __restrict__ bias_ext, float* __restrict__ Pout,
    ushort* __restrict__ HTb) {
    int tid = threadIdx.x;
    int wid = tid >> 6, lane = tid & 63;
    int lrow = lane & 15, kg8 = (lane >> 4) << 3;
    int mbase = blockIdx.x * 64 + wid * 32;
    int nbase = blockIdx.y * 32;
    int rA0 = mbase + lrow, rA1 = rA0 + 16;
    int cB0 = nbase + lrow, cB1 = cB0 + 16;

    f32x4 acc00 = {0.f, 0.f, 0.f, 0.f};
    f32x4 acc01 = acc00, acc10 = acc00, acc11 = acc00;
    bf16x8 pa0h, pa0l, pa1h, pa1l, pb0h, pb0l, pb1h, pb1l;
    bf16x8 qa0h, qa0l, qa1h, qa1l, qb0h, qb0l, qb1h, qb1l;

    LOADSET(p, 0)
#pragma unroll
    for (int ks = 0; ks < 16; ks += 2) {
        LOADSET(q, ks + 1)
        MFMASET(p)
        int kn = (ks + 2) & 15;      // last iter: dummy reload of 0 (unused)
        LOADSET(p, kn)
        MFMASET(q)
    }

    int r0 = (lane >> 4) << 2;
    int col0 = nbase + lrow;
    int col1 = col0 + 16;
    float bv0 = bias_ext[col0];
    float bv1 = bias_ext[col1];

    if (nbase >= C_HT && nbase < C_HT + 512) {
        int o0 = col0 - C_HT, o1 = col1 - C_HT;
#pragma unroll
        for (int r = 0; r < 4; ++r) {
            int row0 = mbase + r0 + r;
            int row1 = row0 + 16;
            HTb[(size_t)row0 * 512 + o0] = f2bf(acc00[r] + bv0);
            HTb[(size_t)row0 * 512 + o1] = f2bf(acc01[r] + bv1);
            HTb[(size_t)row1 * 512 + o0] = f2bf(acc10[r] + bv0);
            HTb[(size_t)row1 * 512 + o1] = f2bf(acc11[r] + bv1);
        }
    } else {
#pragma unroll
        for (int r = 0; r < 4; ++r) {
            int row0 = mbase + r0 + r;
            int row1 = row0 + 16;
            Pout[(size_t)row0 * NP + col0] = acc00[r] + bv0;
            Pout[(size_t)row0 * NP + col1] = acc01[r] + bv1;
            Pout[(size_t)row1 * NP + col0] = acc10[r] + bv0;
            Pout[(size_t)row1 * NP + col1] = acc11[r] + bv1;
        }
    }
}

// ================= k5: scores lookup + normalize + A@HTb(bf16) + relu =================
__global__ __launch_bounds__(128) void k5_out(
    const float* __restrict__ P, const int* __restrict__ dep,
    const ushort* __restrict__ HTb, const float* __restrict__ bias,
    float* __restrict__ out) {
    int row = blockIdx.x;        // 1024
    int b = row >> 7;
    int tid = threadIdx.x;       // 128
    __shared__ float comb[DEPN];
    __shared__ float a[NL];
    __shared__ float red[2];
    __shared__ float sumv;

    const float* Prow = P + (size_t)row * NP;
    float4 p1 = *(const float4*)(Prow + C_P1 + tid * 4);
    float4 p2 = *(const float4*)(Prow + C_P2 + tid * 4);
    float lc = p1.x * p2.x + p1.y * p2.y + p1.z * p2.z + p1.w * p2.w;
    for (int off = 32; off; off >>= 1) lc += __shfl_down(lc, off, 64);
    if ((tid & 63) == 0) red[tid >> 6] = lc;
    if (tid < DEPN) comb[tid] = Prow[C_D1 + tid] + Prow[C_D2 + tid];
    __syncthreads();

    float c0 = red[0] + red[1];
    int tt = dep[(size_t)row * NL + tid];
    float sc = (tt != 0) ? expf(c0 + comb[tt]) : 0.f;
    a[tid] = sc;
    __syncthreads();
    if (tid < 64) {
        float v = a[tid] + a[tid + 64];
        for (int off = 32; off; off >>= 1) v += __shfl_down(v, off, 64);
        if (tid == 0) sumv = v;
    }
    __syncthreads();
    float inv = 1.0f / (sumv + 1e-6f);
    if (tid < NL) a[tid] *= inv;
    __syncthreads();

    // out = relu(sum_j a[j]*HTb[b*128+j][4 o's] + bias)   (bf16 HT)
    const ushort* htb = HTb + (size_t)b * NL * 512 + tid * 4;
    float sx = 0.f, sy = 0.f, sz = 0.f, sw = 0.f;
#pragma unroll 8
    for (int j = 0; j < NL; j += 2) {
        float a0 = a[j], a1 = a[j + 1];
        ushort4 v0 = *(const ushort4*)(htb + (size_t)j * 512);
        ushort4 v1 = *(const ushort4*)(htb + (size_t)(j + 1) * 512);
        sx += a0 * bf2f(v0.x) + a1 * bf2f(v1.x);
        sy += a0 * bf2f(v0.y) + a1 * bf2f(v1.y);
        sz += a0 * bf2f(v0.z) + a1 * bf2f(v1.z);
        sw += a0 * bf2f(v0.w) + a1 * bf2f(v1.w);
    }
    float4 bv = *(const float4*)&bias[tid * 4];
    float4 o;
    o.x = fmaxf(sx + bv.x, 0.f);
    o.y = fmaxf(sy + bv.y, 0.f);
    o.z = fmaxf(sz + bv.z, 0.f);
    o.w = fmaxf(sw + bv.w, 0.f);
    *(float4*)&out[(size_t)row * 512 + tid * 4] = o;
}

extern "C" void kernel_launch(void* const* d_in, const int* in_sizes, int n_in,
                              void* d_out, int out_size, void* d_ws, size_t ws_size,
                              hipStream_t stream) {
    const float* h    = (const float*)d_in[0];
    const int* dep    = (const int*)d_in[1];
    const unsigned char* mask = (const unsigned char*)d_in[2];
    const float* emb  = (const float*)d_in[3];
    const float* W1   = (const float*)d_in[4];
    const float* b1   = (const float*)d_in[5];
    const float* W2   = (const float*)d_in[6];
    const float* b2   = (const float*)d_in[7];
    const float* Wg   = (const float*)d_in[8];
    const float* bg   = (const float*)d_in[9];
    const float* bias = (const float*)d_in[10];
    float* out = (float*)d_out;

    char* p = (char*)d_ws;
    ushort* A_hi = (ushort*)p;  p += (size_t)1024 * 512 * 2;   // 1 MB
    ushort* A_lo = (ushort*)p;  p += (size_t)1024 * 512 * 2;
    ushort* B_hi = (ushort*)p;  p += (size_t)NP * 512 * 2;     // 1.7 MB
    ushort* B_lo = (ushort*)p;  p += (size_t)NP * 512 * 2;
    ushort* HTb = (ushort*)p;   p += (size_t)1024 * 512 * 2;   // 1 MB
    float* bias_ext = (float*)p; p += NP * 4;
    float* Pout = (float*)p;    // 1024*1664*4 = 6.8 MB (HT region unused)

    k_prep<<<522, 256, 0, stream>>>(h, mask, emb, W1, W2, Wg, b1, b2, bg,
                                    A_hi, A_lo, B_hi, B_lo, bias_ext);
    dim3 g3(16, 52);
    k3_gemm<<<g3, 128, 0, stream>>>(A_hi, A_lo, B_hi, B_lo, bias_ext, Pout, HTb);
    k5_out<<<NBATCH * NL, 128, 0, stream>>>(Pout, dep, HTb, bias, out);
}

// Round 13
// 55.931 us; speedup vs baseline: 1.2572x; 1.0322x over previous
//
#include <hip/hip_runtime.h>
#include <hip/hip_bf16.h>
#include <math.h>

#define NBATCH 8
#define NL 128
#define IND 512
#define DEPN 45
#define DEPD 16
#define WCOLS 528          // IN_DIM + DEP_DIM
#define NP 1664            // extended width (P1|P2|HT|D1|D2|pad)
#define C_P1 0
#define C_P2 512
#define C_HT 1024
#define C_D1 1536
#define C_D2 1581
#define C_PAD 1626

typedef __attribute__((ext_vector_type(8))) short bf16x8;
typedef __attribute__((ext_vector_type(4))) float f32x4;

__device__ inline ushort f2bf(float x) {
    __hip_bfloat16 b = __float2bfloat16(x);
    return *reinterpret_cast<ushort*>(&b);
}
__device__ inline float bf2f(ushort u) {
    __hip_bfloat16 b;
    *reinterpret_cast<ushort*>(&b) = u;
    return __bfloat162float(b);
}

__device__ __forceinline__ void gl16(const ushort* g, ushort* l) {
    __builtin_amdgcn_global_load_lds(
        (const __attribute__((address_space(1))) unsigned int*)g,
        (__attribute__((address_space(3))) unsigned int*)l, 16, 0, 0);
}

// ================= k_prep (merged; unchanged from R12) =================
__global__ __launch_bounds__(256) void k_prep(
    const float* __restrict__ h, const unsigned char* __restrict__ mask,
    const float* __restrict__ emb,
    const float* __restrict__ W1, const float* __restrict__ W2,
    const float* __restrict__ Wg,
    const float* __restrict__ b1, const float* __restrict__ b2,
    const float* __restrict__ bg,
    ushort* __restrict__ A_hi, ushort* __restrict__ A_lo,
    ushort* __restrict__ B_hi, ushort* __restrict__ B_lo,
    float* __restrict__ bias_ext) {
    int bid = blockIdx.x;
    int tid = threadIdx.x;

    if (bid < 64) {
        int rb = bid * 16;
        int b = rb >> 7;
        __shared__ int sflag, smin, smax;
        __shared__ float w16[16];
        if (tid == 0) { sflag = 0; smin = NL; smax = -1; }
        __syncthreads();
        const int* mi = (const int*)mask;
        if (tid < 128) {
            int v0 = mi[tid], v1 = mi[tid + 128];
            if ((unsigned)v0 > 1u || (unsigned)v1 > 1u) atomicOr(&sflag, 1);
        }
        __syncthreads();
        if (tid < 128) {
            int mval = sflag ? (int)mask[b * NL + tid] : mi[b * NL + tid];
            if (mval) { atomicMin(&smin, tid); atomicMax(&smax, tid); }
        }
        __syncthreads();
        if (tid < 16) {
            int any = (smax >= 0);
            int s = any ? smin : 0;
            int e = any ? smax : (NL - 1);
            int i = (rb & 127) + tid;
            const float invL = 1.0f / (float)NL;
            float w;
            if (i < s)      w = 1.0f - (float)(s - i) * invL;
            else if (i > e) w = 1.0f - (float)(i - e) * invL;
            else            w = 0.0f;
            int mval = sflag ? (int)mask[b * NL + i] : mi[b * NL + i];
            if (mval) w = 0.0f;
            w16[tid] = w;
        }
        __syncthreads();
        for (int idx = tid; idx < 16 * 128; idx += 256) {
            int r = idx >> 7, dc = (idx & 127) << 2;
            float4 hv = *(const float4*)&h[(size_t)(rb + r) * IND + dc];
            float wv = w16[r];
            hv.x *= wv; hv.y *= wv; hv.z *= wv; hv.w *= wv;
            ushort4 hi4, lo4;
            hi4.x = f2bf(hv.x); hi4.y = f2bf(hv.y); hi4.z = f2bf(hv.z); hi4.w = f2bf(hv.w);
            lo4.x = f2bf(hv.x - bf2f(hi4.x));
            lo4.y = f2bf(hv.y - bf2f(hi4.y));
            lo4.z = f2bf(hv.z - bf2f(hi4.z));
            lo4.w = f2bf(hv.w - bf2f(hi4.w));
            *(ushort4*)&A_hi[(size_t)(rb + r) * IND + dc] = hi4;
            *(ushort4*)&A_lo[(size_t)(rb + r) * IND + dc] = lo4;
        }
        if (bid == 0) {
            for (int i = tid; i < 512; i += 256) {
                bias_ext[C_P1 + i] = b1[i];
                bias_ext[C_P2 + i] = b2[i];
                bias_ext[C_HT + i] = bg[i];
            }
            if (tid < NP - C_PAD) bias_ext[C_PAD + tid] = 0.f;
        }
    } else if (bid < 160) {
        int nb = (bid - 64) * 16;
        for (int idx = tid; idx < 16 * 128; idx += 256) {
            int r = idx >> 7, dc = (idx & 127) << 2;
            int n = nb + r;
            const float* src;
            if (n < 512)       src = W1 + (size_t)n * WCOLS + dc;
            else if (n < 1024) src = W2 + (size_t)(n - 512) * WCOLS + dc;
            else               src = Wg + (size_t)(n - 1024) * IND + dc;
            float4 wv = *(const float4*)src;
            ushort4 hi4, lo4;
            hi4.x = f2bf(wv.x); hi4.y = f2bf(wv.y); hi4.z = f2bf(wv.z); hi4.w = f2bf(wv.w);
            lo4.x = f2bf(wv.x - bf2f(hi4.x));
            lo4.y = f2bf(wv.y - bf2f(hi4.y));
            lo4.z = f2bf(wv.z - bf2f(hi4.z));
            lo4.w = f2bf(wv.w - bf2f(hi4.w));
            *(ushort4*)&B_hi[(size_t)n * IND + dc] = hi4;
            *(ushort4*)&B_lo[(size_t)n * IND + dc] = lo4;
        }
    } else if (bid < 162) {
        int nb = 1626 + (bid - 160) * 19;
        ushort4 z4 = {0, 0, 0, 0};
        for (int idx = tid; idx < 19 * 128; idx += 256) {
            int r = idx >> 7, dc = (idx & 127) << 2;
            *(ushort4*)&B_hi[(size_t)(nb + r) * IND + dc] = z4;
            *(ushort4*)&B_lo[(size_t)(nb + r) * IND + dc] = z4;
        }
    } else {
        int zi = bid - 162;
        int t = zi % 45;
        int m = (zi / 45) & 1;
        int dq = zi / 90;
        __shared__ float es[DEPD];
        __shared__ float ys[512];
        __shared__ float y1s[512];
        __shared__ float part[256];
        if (tid < DEPD) es[tid] = emb[t * DEPD + tid];
        __syncthreads();
        const float* Wdep = (m == 0) ? W2 : W1;
        for (int o = tid; o < 512; o += 256) {
            float s = 0.f;
#pragma unroll
            for (int e = 0; e < DEPD; e++) s += es[e] * Wdep[o * WCOLS + IND + e];
            ys[o] = s;
        }
        if (m == 0 && dq == 0) {
            for (int o = tid; o < 512; o += 256) {
                float s = 0.f;
#pragma unroll
                for (int e = 0; e < DEPD; e++) s += es[e] * W1[o * WCOLS + IND + e];
                y1s[o] = s;
            }
        }
        __syncthreads();
        int dloc = tid & 127, half = tid >> 7;
        const float* Wsrc = (m == 0) ? W1 : W2;
        int d = dq * 128 + dloc;
        int obase = half * 256;
        float s = 0.f;
#pragma unroll 16
        for (int oo = 0; oo < 256; oo++)
            s += Wsrc[(size_t)(obase + oo) * WCOLS + d] * ys[obase + oo];
        part[tid] = s;
        __syncthreads();
        int row = ((m == 0) ? C_D1 : C_D2) + t;
        if (half == 0) {
            float tot = part[dloc] + part[128 + dloc];
            ushort hi = f2bf(tot);
            B_hi[(size_t)row * IND + d] = hi;
            B_lo[(size_t)row * IND + d] = f2bf(tot - bf2f(hi));
        }
        if (dq == 0 && tid < 64) {
            const float* bb = (m == 0) ? b1 : b2;
            float sb = 0.f;
#pragma unroll
            for (int k = 0; k < 8; k++) sb += bb[tid + k * 64] * ys[tid + k * 64];
            if (m == 0) {
#pragma unroll
                for (int k = 0; k < 8; k++) sb += y1s[tid + k * 64] * ys[tid + k * 64];
            }
            for (int off = 32; off; off >>= 1) sb += __shfl_down(sb, off, 64);
            if (tid == 0) bias_ext[row] = sb;
        }
    }
}

// ================= k3: LDS-shared MFMA GEMM =================
// Grid (32 m, 26 n) = 832 blocks; 128 thr = 2 waves. Block tile 32m x 64n;
// wave w owns n-half w*32; wave tile 32x32 (2x2 16x16x32 frags, hi/lo 3-term).
// K in 4 chunks of 128, staged to LDS via global_load_lds ([granule][row]
// layout: conflict-free ds_read_b128, linear dest for gload_lds).
// LDS 48 KB -> 3 blocks/CU; staging of one block overlaps compute of another.
__global__ __launch_bounds__(128) void k3_gemm(
    const ushort* __restrict__ A_hi, const ushort* __restrict__ A_lo,
    const ushort* __restrict__ B_hi, const ushort* __restrict__ B_lo,
    const float* __restrict__ bias_ext, float* __restrict__ Pout,
    ushort* __restrict__ HTb) {
    int tid = threadIdx.x;
    int wid = tid >> 6, lane = tid & 63;
    int lrow = lane & 15;
    int mbase = blockIdx.x * 32;
    int nbase = blockIdx.y * 64;

    __shared__ ushort Ah[16 * 32 * 8];   // [granule][32 rows][8 elems]  8 KB
    __shared__ ushort Al[16 * 32 * 8];
    __shared__ ushort Bh[16 * 64 * 8];   // [granule][64 rows][8 elems] 16 KB
    __shared__ ushort Bl[16 * 64 * 8];

    // per-lane global source bases for staging
    const ushort* aSrcH = A_hi + (size_t)(mbase + (lane & 31)) * IND + ((lane >> 5) << 3);
    const ushort* aSrcL = A_lo + (size_t)(mbase + (lane & 31)) * IND + ((lane >> 5) << 3);
    const ushort* bSrcH = B_hi + (size_t)(nbase + lane) * IND;
    const ushort* bSrcL = B_lo + (size_t)(nbase + lane) * IND;

#define STAGE(C) { \
    int ck = (C) * 128; \
    if (wid == 0) { \
        _Pragma("unroll") \
        for (int i = 0; i < 8; i++) gl16(aSrcH + ck + (i << 4), &Ah[i << 9]); \
        _Pragma("unroll") \
        for (int i = 0; i < 8; i++) gl16(aSrcL + ck + (i << 4), &Al[i << 9]); \
        _Pragma("unroll") \
        for (int g = 0; g < 8; g++) gl16(bSrcH + ck + (g << 3), &Bh[g << 9]); \
    } else { \
        _Pragma("unroll") \
        for (int g = 8; g < 16; g++) gl16(bSrcH + ck + (g << 3), &Bh[g << 9]); \
        _Pragma("unroll") \
        for (int g = 0; g < 16; g++) gl16(bSrcL + ck + (g << 3), &Bl[g << 9]); \
    } }

    f32x4 acc00 = {0.f, 0.f, 0.f, 0.f};
    f32x4 acc01 = acc00, acc10 = acc00, acc11 = acc00;

    STAGE(0)
    for (int c = 0; c < 4; c++) {
        __syncthreads();                 // staging visible (vmcnt drained)
#pragma unroll
        for (int KS = 0; KS < 4; KS++) {
            int gl = (KS << 2) + (lane >> 4);
            int ga = ((gl << 5) + lrow) << 3;
            int gb = ((gl << 6) + (wid << 5) + lrow) << 3;
            bf16x8 a0h = *(const bf16x8*)&Ah[ga];
            bf16x8 a0l = *(const bf16x8*)&Al[ga];
            bf16x8 a1h = *(const bf16x8*)&Ah[ga + 128];
            bf16x8 a1l = *(const bf16x8*)&Al[ga + 128];
            bf16x8 b0h = *(const bf16x8*)&Bh[gb];
            bf16x8 b0l = *(const bf16x8*)&Bl[gb];
            bf16x8 b1h = *(const bf16x8*)&Bh[gb + 128];
            bf16x8 b1l = *(const bf16x8*)&Bl[gb + 128];
            acc00 = __builtin_amdgcn_mfma_f32_16x16x32_bf16(a0h, b0h, acc00, 0, 0, 0);
            acc00 = __builtin_amdgcn_mfma_f32_16x16x32_bf16(a0h, b0l, acc00, 0, 0, 0);
            acc00 = __builtin_amdgcn_mfma_f32_16x16x32_bf16(a0l, b0h, acc00, 0, 0, 0);
            acc01 = __builtin_amdgcn_mfma_f32_16x16x32_bf16(a0h, b1h, acc01, 0, 0, 0);
            acc01 = __builtin_amdgcn_mfma_f32_16x16x32_bf16(a0h, b1l, acc01, 0, 0, 0);
            acc01 = __builtin_amdgcn_mfma_f32_16x16x32_bf16(a0l, b1h, acc01, 0, 0, 0);
            acc10 = __builtin_amdgcn_mfma_f32_16x16x32_bf16(a1h, b0h, acc10, 0, 0, 0);
            acc10 = __builtin_amdgcn_mfma_f32_16x16x32_bf16(a1h, b0l, acc10, 0, 0, 0);
            acc10 = __builtin_amdgcn_mfma_f32_16x16x32_bf16(a1l, b0h, acc10, 0, 0, 0);
            acc11 = __builtin_amdgcn_mfma_f32_16x16x32_bf16(a1h, b1h, acc11, 0, 0, 0);
            acc11 = __builtin_amdgcn_mfma_f32_16x16x32_bf16(a1h, b1l, acc11, 0, 0, 0);
            acc11 = __builtin_amdgcn_mfma_f32_16x16x32_bf16(a1l, b1h, acc11, 0, 0, 0);
        }
        if (c < 3) {
            __syncthreads();             // all waves done reading before overwrite
            STAGE(c + 1)
        }
    }
#undef STAGE

    int r0 = (lane >> 4) << 2;
    int colb = nbase + (wid << 5);
    int col0 = colb + lrow;
    int col1 = col0 + 16;
    float bv0 = bias_ext[col0];
    float bv1 = bias_ext[col1];

    if (colb >= C_HT && colb < C_HT + 512) {
        int o0 = col0 - C_HT, o1 = col1 - C_HT;
#pragma unroll
        for (int r = 0; r < 4; ++r) {
            int row0 = mbase + r0 + r;
            int row1 = row0 + 16;
            HTb[(size_t)row0 * 512 + o0] = f2bf(acc00[r] + bv0);
            HTb[(size_t)row0 * 512 + o1] = f2bf(acc01[r] + bv1);
            HTb[(size_t)row1 * 512 + o0] = f2bf(acc10[r] + bv0);
            HTb[(size_t)row1 * 512 + o1] = f2bf(acc11[r] + bv1);
        }
    } else {
#pragma unroll
        for (int r = 0; r < 4; ++r) {
            int row0 = mbase + r0 + r;
            int row1 = row0 + 16;
            Pout[(size_t)row0 * NP + col0] = acc00[r] + bv0;
            Pout[(size_t)row0 * NP + col1] = acc01[r] + bv1;
            Pout[(size_t)row1 * NP + col0] = acc10[r] + bv0;
            Pout[(size_t)row1 * NP + col1] = acc11[r] + bv1;
        }
    }
}

// ================= k5: scores + normalize + A@HTb(bf16) + relu (R12) =================
__global__ __launch_bounds__(128) void k5_out(
    const float* __restrict__ P, const int* __restrict__ dep,
    const ushort* __restrict__ HTb, const float* __restrict__ bias,
    float* __restrict__ out) {
    int row = blockIdx.x;        // 1024
    int b = row >> 7;
    int tid = threadIdx.x;       // 128
    __shared__ float comb[DEPN];
    __shared__ float a[NL];
    __shared__ float red[2];
    __shared__ float sumv;

    const float* Prow = P + (size_t)row * NP;
    float4 p1 = *(const float4*)(Prow + C_P1 + tid * 4);
    float4 p2 = *(const float4*)(Prow + C_P2 + tid * 4);
    float lc = p1.x * p2.x + p1.y * p2.y + p1.z * p2.z + p1.w * p2.w;
    for (int off = 32; off; off >>= 1) lc += __shfl_down(lc, off, 64);
    if ((tid & 63) == 0) red[tid >> 6] = lc;
    if (tid < DEPN) comb[tid] = Prow[C_D1 + tid] + Prow[C_D2 + tid];
    __syncthreads();

    float c0 = red[0] + red[1];
    int tt = dep[(size_t)row * NL + tid];
    float sc = (tt != 0) ? expf(c0 + comb[tt]) : 0.f;
    a[tid] = sc;
    __syncthreads();
    if (tid < 64) {
        float v = a[tid] + a[tid + 64];
        for (int off = 32; off; off >>= 1) v += __shfl_down(v, off, 64);
        if (tid == 0) sumv = v;
    }
    __syncthreads();
    float inv = 1.0f / (sumv + 1e-6f);
    if (tid < NL) a[tid] *= inv;
    __syncthreads();

    const ushort* htb = HTb + (size_t)b * NL * 512 + tid * 4;
    float sx = 0.f, sy = 0.f, sz = 0.f, sw = 0.f;
#pragma unroll 8
    for (int j = 0; j < NL; j += 2) {
        float a0 = a[j], a1 = a[j + 1];
        ushort4 v0 = *(const ushort4*)(htb + (size_t)j * 512);
        ushort4 v1 = *(const ushort4*)(htb + (size_t)(j + 1) * 512);
        sx += a0 * bf2f(v0.x) + a1 * bf2f(v1.x);
        sy += a0 * bf2f(v0.y) + a1 * bf2f(v1.y);
        sz += a0 * bf2f(v0.z) + a1 * bf2f(v1.z);
        sw += a0 * bf2f(v0.w) + a1 * bf2f(v1.w);
    }
    float4 bv = *(const float4*)&bias[tid * 4];
    float4 o;
    o.x = fmaxf(sx + bv.x, 0.f);
    o.y = fmaxf(sy + bv.y, 0.f);
    o.z = fmaxf(sz + bv.z, 0.f);
    o.w = fmaxf(sw + bv.w, 0.f);
    *(float4*)&out[(size_t)row * 512 + tid * 4] = o;
}

extern "C" void kernel_launch(void* const* d_in, const int* in_sizes, int n_in,
                              void* d_out, int out_size, void* d_ws, size_t ws_size,
                              hipStream_t stream) {
    const float* h    = (const float*)d_in[0];
    const int* dep    = (const int*)d_in[1];
    const unsigned char* mask = (const unsigned char*)d_in[2];
    const float* emb  = (const float*)d_in[3];
    const float* W1   = (const float*)d_in[4];
    const float* b1   = (const float*)d_in[5];
    const float* W2   = (const float*)d_in[6];
    const float* b2   = (const float*)d_in[7];
    const float* Wg   = (const float*)d_in[8];
    const float* bg   = (const float*)d_in[9];
    const float* bias = (const float*)d_in[10];
    float* out = (float*)d_out;

    char* p = (char*)d_ws;
    ushort* A_hi = (ushort*)p;  p += (size_t)1024 * 512 * 2;   // 1 MB
    ushort* A_lo = (ushort*)p;  p += (size_t)1024 * 512 * 2;
    ushort* B_hi = (ushort*)p;  p += (size_t)NP * 512 * 2;     // 1.7 MB
    ushort* B_lo = (ushort*)p;  p += (size_t)NP * 512 * 2;
    ushort* HTb = (ushort*)p;   p += (size_t)1024 * 512 * 2;   // 1 MB
    float* bias_ext = (float*)p; p += NP * 4;
    float* Pout = (float*)p;    // 1024*1664*4 (HT region unused)

    k_prep<<<522, 256, 0, stream>>>(h, mask, emb, W1, W2, Wg, b1, b2, bg,
                                    A_hi, A_lo, B_hi, B_lo, bias_ext);
    dim3 g3(32, 26);
    k3_gemm<<<g3, 128, 0, stream>>>(A_hi, A_lo, B_hi, B_lo, bias_ext, Pout, HTb);
    k5_out<<<NBATCH * NL, 128, 0, stream>>>(Pout, dep, HTb, bias, out);
}

// Round 14
// 54.638 us; speedup vs baseline: 1.2869x; 1.0237x over previous
//
#include <hip/hip_runtime.h>
#include <hip/hip_bf16.h>
#include <math.h>

#define NBATCH 8
#define NL 128
#define IND 512
#define DEPN 45
#define DEPD 16
#define WCOLS 528          // IN_DIM + DEP_DIM
#define NP 1664            // extended width (P1|P2|HT|D1|D2|pad)
#define C_P1 0
#define C_P2 512
#define C_HT 1024
#define C_D1 1536
#define C_D2 1581
#define C_PAD 1626

typedef __attribute__((ext_vector_type(8))) short bf16x8;
typedef __attribute__((ext_vector_type(4))) float f32x4;

__device__ inline ushort f2bf(float x) {
    __hip_bfloat16 b = __float2bfloat16(x);
    return *reinterpret_cast<ushort*>(&b);
}
__device__ inline float bf2f(ushort u) {
    __hip_bfloat16 b;
    *reinterpret_cast<ushort*>(&b) = u;
    return __bfloat162float(b);
}

__device__ __forceinline__ void gl16(const ushort* g, ushort* l) {
    __builtin_amdgcn_global_load_lds(
        (const __attribute__((address_space(1))) unsigned int*)g,
        (__attribute__((address_space(3))) unsigned int*)l, 16, 0, 0);
}

// ================= k_prep =================
// [0,64):    A_hi/A_lo = bf16-split of h*wpos (16 rows); blk0: bias_ext base/pad
// [64,160):  B rows 0..1535 = split of W1h|W2h|Wg (16 rows each)
// [160,162): zero B pad rows 1626..1663 (19 each)
// [162,234): Z rows, 5-t tiles: zi=(bid-162); m=zi/36, dq=(zi%36)/9, tq=zi%9
// [234,324): D-bias: zi2=(bid-234); t=zi2%45, m=zi2/45
__global__ __launch_bounds__(256) void k_prep(
    const float* __restrict__ h, const unsigned char* __restrict__ mask,
    const float* __restrict__ emb,
    const float* __restrict__ W1, const float* __restrict__ W2,
    const float* __restrict__ Wg,
    const float* __restrict__ b1, const float* __restrict__ b2,
    const float* __restrict__ bg,
    ushort* __restrict__ A_hi, ushort* __restrict__ A_lo,
    ushort* __restrict__ B_hi, ushort* __restrict__ B_lo,
    float* __restrict__ bias_ext) {
    int bid = blockIdx.x;
    int tid = threadIdx.x;

    if (bid < 64) {
        int rb = bid * 16;
        int b = rb >> 7;
        __shared__ int sflag, smin, smax;
        __shared__ float w16[16];
        if (tid == 0) { sflag = 0; smin = NL; smax = -1; }
        __syncthreads();
        const int* mi = (const int*)mask;
        if (tid < 128) {
            int v0 = mi[tid], v1 = mi[tid + 128];
            if ((unsigned)v0 > 1u || (unsigned)v1 > 1u) atomicOr(&sflag, 1);
        }
        __syncthreads();
        if (tid < 128) {
            int mval = sflag ? (int)mask[b * NL + tid] : mi[b * NL + tid];
            if (mval) { atomicMin(&smin, tid); atomicMax(&smax, tid); }
        }
        __syncthreads();
        if (tid < 16) {
            int any = (smax >= 0);
            int s = any ? smin : 0;
            int e = any ? smax : (NL - 1);
            int i = (rb & 127) + tid;
            const float invL = 1.0f / (float)NL;
            float w;
            if (i < s)      w = 1.0f - (float)(s - i) * invL;
            else if (i > e) w = 1.0f - (float)(i - e) * invL;
            else            w = 0.0f;
            int mval = sflag ? (int)mask[b * NL + i] : mi[b * NL + i];
            if (mval) w = 0.0f;
            w16[tid] = w;
        }
        __syncthreads();
        for (int idx = tid; idx < 16 * 128; idx += 256) {
            int r = idx >> 7, dc = (idx & 127) << 2;
            float4 hv = *(const float4*)&h[(size_t)(rb + r) * IND + dc];
            float wv = w16[r];
            hv.x *= wv; hv.y *= wv; hv.z *= wv; hv.w *= wv;
            ushort4 hi4, lo4;
            hi4.x = f2bf(hv.x); hi4.y = f2bf(hv.y); hi4.z = f2bf(hv.z); hi4.w = f2bf(hv.w);
            lo4.x = f2bf(hv.x - bf2f(hi4.x));
            lo4.y = f2bf(hv.y - bf2f(hi4.y));
            lo4.z = f2bf(hv.z - bf2f(hi4.z));
            lo4.w = f2bf(hv.w - bf2f(hi4.w));
            *(ushort4*)&A_hi[(size_t)(rb + r) * IND + dc] = hi4;
            *(ushort4*)&A_lo[(size_t)(rb + r) * IND + dc] = lo4;
        }
        if (bid == 0) {
            for (int i = tid; i < 512; i += 256) {
                bias_ext[C_P1 + i] = b1[i];
                bias_ext[C_P2 + i] = b2[i];
                bias_ext[C_HT + i] = bg[i];
            }
            if (tid < NP - C_PAD) bias_ext[C_PAD + tid] = 0.f;
        }
    } else if (bid < 160) {
        int nb = (bid - 64) * 16;
        for (int idx = tid; idx < 16 * 128; idx += 256) {
            int r = idx >> 7, dc = (idx & 127) << 2;
            int n = nb + r;
            const float* src;
            if (n < 512)       src = W1 + (size_t)n * WCOLS + dc;
            else if (n < 1024) src = W2 + (size_t)(n - 512) * WCOLS + dc;
            else               src = Wg + (size_t)(n - 1024) * IND + dc;
            float4 wv = *(const float4*)src;
            ushort4 hi4, lo4;
            hi4.x = f2bf(wv.x); hi4.y = f2bf(wv.y); hi4.z = f2bf(wv.z); hi4.w = f2bf(wv.w);
            lo4.x = f2bf(wv.x - bf2f(hi4.x));
            lo4.y = f2bf(wv.y - bf2f(hi4.y));
            lo4.z = f2bf(wv.z - bf2f(hi4.z));
            lo4.w = f2bf(wv.w - bf2f(hi4.w));
            *(ushort4*)&B_hi[(size_t)n * IND + dc] = hi4;
            *(ushort4*)&B_lo[(size_t)n * IND + dc] = lo4;
        }
    } else if (bid < 162) {
        int nb = 1626 + (bid - 160) * 19;
        ushort4 z4 = {0, 0, 0, 0};
        for (int idx = tid; idx < 19 * 128; idx += 256) {
            int r = idx >> 7, dc = (idx & 127) << 2;
            *(ushort4*)&B_hi[(size_t)(nb + r) * IND + dc] = z4;
            *(ushort4*)&B_lo[(size_t)(nb + r) * IND + dc] = z4;
        }
    } else if (bid < 234) {
        // ---- Z rows, 5 t's per block ----
        int zi = bid - 162;               // 0..71
        int m = zi / 36;
        int rest = zi % 36;
        int dq = rest / 9;
        int tq = rest % 9;
        int tb = tq * 5;
        __shared__ float es5[5][DEPD];
        __shared__ float ys5[5][512];
        __shared__ float part[5][256];
        if (tid < 5 * DEPD) es5[tid >> 4][tid & 15] = emb[(tb + (tid >> 4)) * DEPD + (tid & 15)];
        __syncthreads();
        const float* Wdep = (m == 0) ? W2 : W1;
        for (int idx = tid; idx < 5 * 512; idx += 256) {
            int tt = idx >> 9, o = idx & 511;
            float s = 0.f;
#pragma unroll
            for (int e = 0; e < DEPD; e++) s += es5[tt][e] * Wdep[o * WCOLS + IND + e];
            ys5[tt][o] = s;
        }
        __syncthreads();
        int dloc = tid & 127, half = tid >> 7;
        const float* Wsrc = (m == 0) ? W1 : W2;
        int d = dq * 128 + dloc;
        int obase = half * 256;
        float ac0 = 0.f, ac1 = 0.f, ac2 = 0.f, ac3 = 0.f, ac4 = 0.f;
#pragma unroll 8
        for (int oo = 0; oo < 256; oo++) {
            float w = Wsrc[(size_t)(obase + oo) * WCOLS + d];
            int o = obase + oo;
            ac0 += w * ys5[0][o];
            ac1 += w * ys5[1][o];
            ac2 += w * ys5[2][o];
            ac3 += w * ys5[3][o];
            ac4 += w * ys5[4][o];
        }
        part[0][tid] = ac0; part[1][tid] = ac1; part[2][tid] = ac2;
        part[3][tid] = ac3; part[4][tid] = ac4;
        __syncthreads();
        if (half == 0) {
#pragma unroll
            for (int tt = 0; tt < 5; tt++) {
                float tot = part[tt][dloc] + part[tt][128 + dloc];
                int row = ((m == 0) ? C_D1 : C_D2) + tb + tt;
                ushort hi = f2bf(tot);
                B_hi[(size_t)row * IND + d] = hi;
                B_lo[(size_t)row * IND + d] = f2bf(tot - bf2f(hi));
            }
        }
    } else {
        // ---- D-bias per (t, m) ----
        int zi2 = bid - 234;              // 0..89
        int t = zi2 % 45;
        int m = zi2 / 45;
        __shared__ float es[DEPD];
        __shared__ float ys[512];
        __shared__ float y1s[512];
        if (tid < DEPD) es[tid] = emb[t * DEPD + tid];
        __syncthreads();
        const float* Wdep = (m == 0) ? W2 : W1;
        for (int o = tid; o < 512; o += 256) {
            float s = 0.f;
#pragma unroll
            for (int e = 0; e < DEPD; e++) s += es[e] * Wdep[o * WCOLS + IND + e];
            ys[o] = s;
        }
        if (m == 0) {
            for (int o = tid; o < 512; o += 256) {
                float s = 0.f;
#pragma unroll
                for (int e = 0; e < DEPD; e++) s += es[e] * W1[o * WCOLS + IND + e];
                y1s[o] = s;
            }
        }
        __syncthreads();
        if (tid < 64) {
            const float* bb = (m == 0) ? b1 : b2;
            float sb = 0.f;
#pragma unroll
            for (int k = 0; k < 8; k++) sb += bb[tid + k * 64] * ys[tid + k * 64];
            if (m == 0) {
#pragma unroll
                for (int k = 0; k < 8; k++) sb += y1s[tid + k * 64] * ys[tid + k * 64];
            }
            for (int off = 32; off; off >>= 1) sb += __shfl_down(sb, off, 64);
            if (tid == 0) bias_ext[((m == 0) ? C_D1 : C_D2) + t] = sb;
        }
    }
}

// ================= k3: LDS-shared MFMA GEMM, 64x64 tile =================
// Grid (16, 26) = 416 blocks; 256 thr = 4 waves (2m x 2n wave grid, 32x32 each).
// K-chunk 64 (8 granules); wave w stages one of {Ah, Al, Bh, Bl}.
// LDS 32 KB; [granule][row][8] layout: linear gl16 dest, 2-way ds_read.
__global__ __launch_bounds__(256) void k3_gemm(
    const ushort* __restrict__ A_hi, const ushort* __restrict__ A_lo,
    const ushort* __restrict__ B_hi, const ushort* __restrict__ B_lo,
    const float* __restrict__ bias_ext, float* __restrict__ Pout,
    ushort* __restrict__ HTb) {
    int tid = threadIdx.x;
    int wid = tid >> 6, lane = tid & 63;
    int lrow = lane & 15;
    int mbase = blockIdx.x * 64;
    int nbase = blockIdx.y * 64;
    int mh = (wid >> 1) << 5;
    int nh = (wid & 1) << 5;

    __shared__ ushort Ah[8 * 64 * 8];   // 8 KB each
    __shared__ ushort Al[8 * 64 * 8];
    __shared__ ushort Bh[8 * 64 * 8];
    __shared__ ushort Bl[8 * 64 * 8];

    const ushort* aH = A_hi + (size_t)(mbase + lane) * IND;
    const ushort* aL = A_lo + (size_t)(mbase + lane) * IND;
    const ushort* bH = B_hi + (size_t)(nbase + lane) * IND;
    const ushort* bL = B_lo + (size_t)(nbase + lane) * IND;

#define STAGE(C) { \
    int ck = (C) << 6; \
    if (wid == 0) { \
        _Pragma("unroll") \
        for (int g = 0; g < 8; g++) gl16(aH + ck + (g << 3), &Ah[g << 9]); \
    } else if (wid == 1) { \
        _Pragma("unroll") \
        for (int g = 0; g < 8; g++) gl16(aL + ck + (g << 3), &Al[g << 9]); \
    } else if (wid == 2) { \
        _Pragma("unroll") \
        for (int g = 0; g < 8; g++) gl16(bH + ck + (g << 3), &Bh[g << 9]); \
    } else { \
        _Pragma("unroll") \
        for (int g = 0; g < 8; g++) gl16(bL + ck + (g << 3), &Bl[g << 9]); \
    } }

    f32x4 acc00 = {0.f, 0.f, 0.f, 0.f};
    f32x4 acc01 = acc00, acc10 = acc00, acc11 = acc00;

    STAGE(0)
    for (int c = 0; c < 8; c++) {
        __syncthreads();                 // staged data visible
#pragma unroll
        for (int KS = 0; KS < 2; KS++) {
            int gA = (KS << 2) + (lane >> 4);
            int ga = ((gA << 6) + mh + lrow) << 3;
            int gb = ((gA << 6) + nh + lrow) << 3;
            bf16x8 a0h = *(const bf16x8*)&Ah[ga];
            bf16x8 a0l = *(const bf16x8*)&Al[ga];
            bf16x8 a1h = *(const bf16x8*)&Ah[ga + 128];
            bf16x8 a1l = *(const bf16x8*)&Al[ga + 128];
            bf16x8 b0h = *(const bf16x8*)&Bh[gb];
            bf16x8 b0l = *(const bf16x8*)&Bl[gb];
            bf16x8 b1h = *(const bf16x8*)&Bh[gb + 128];
            bf16x8 b1l = *(const bf16x8*)&Bl[gb + 128];
            acc00 = __builtin_amdgcn_mfma_f32_16x16x32_bf16(a0h, b0h, acc00, 0, 0, 0);
            acc00 = __builtin_amdgcn_mfma_f32_16x16x32_bf16(a0h, b0l, acc00, 0, 0, 0);
            acc00 = __builtin_amdgcn_mfma_f32_16x16x32_bf16(a0l, b0h, acc00, 0, 0, 0);
            acc01 = __builtin_amdgcn_mfma_f32_16x16x32_bf16(a0h, b1h, acc01, 0, 0, 0);
            acc01 = __builtin_amdgcn_mfma_f32_16x16x32_bf16(a0h, b1l, acc01, 0, 0, 0);
            acc01 = __builtin_amdgcn_mfma_f32_16x16x32_bf16(a0l, b1h, acc01, 0, 0, 0);
            acc10 = __builtin_amdgcn_mfma_f32_16x16x32_bf16(a1h, b0h, acc10, 0, 0, 0);
            acc10 = __builtin_amdgcn_mfma_f32_16x16x32_bf16(a1h, b0l, acc10, 0, 0, 0);
            acc10 = __builtin_amdgcn_mfma_f32_16x16x32_bf16(a1l, b0h, acc10, 0, 0, 0);
            acc11 = __builtin_amdgcn_mfma_f32_16x16x32_bf16(a1h, b1h, acc11, 0, 0, 0);
            acc11 = __builtin_amdgcn_mfma_f32_16x16x32_bf16(a1h, b1l, acc11, 0, 0, 0);
            acc11 = __builtin_amdgcn_mfma_f32_16x16x32_bf16(a1l, b1h, acc11, 0, 0, 0);
        }
        if (c < 7) {
            __syncthreads();             // all waves done reading before overwrite
            STAGE(c + 1)
        }
    }
#undef STAGE

    int r0 = (lane >> 4) << 2;
    int colb = nbase + nh;
    int col0 = colb + lrow;
    int col1 = col0 + 16;
    float bv0 = bias_ext[col0];
    float bv1 = bias_ext[col1];
    int rowb = mbase + mh;

    if (colb >= C_HT && colb < C_HT + 512) {
        int o0 = col0 - C_HT, o1 = col1 - C_HT;
#pragma unroll
        for (int r = 0; r < 4; ++r) {
            int row0 = rowb + r0 + r;
            int row1 = row0 + 16;
            HTb[(size_t)row0 * 512 + o0] = f2bf(acc00[r] + bv0);
            HTb[(size_t)row0 * 512 + o1] = f2bf(acc01[r] + bv1);
            HTb[(size_t)row1 * 512 + o0] = f2bf(acc10[r] + bv0);
            HTb[(size_t)row1 * 512 + o1] = f2bf(acc11[r] + bv1);
        }
    } else {
#pragma unroll
        for (int r = 0; r < 4; ++r) {
            int row0 = rowb + r0 + r;
            int row1 = row0 + 16;
            Pout[(size_t)row0 * NP + col0] = acc00[r] + bv0;
            Pout[(size_t)row0 * NP + col1] = acc01[r] + bv1;
            Pout[(size_t)row1 * NP + col0] = acc10[r] + bv0;
            Pout[(size_t)row1 * NP + col1] = acc11[r] + bv1;
        }
    }
}

// ================= k5: 4 rows/block; softmax + shared-HT matmul =================
// grid 256 = 8 b x 32 rowgroups of 4.  256 thr: wave wr owns row wr for
// reductions; phase D: thread owns 2 o-cols, accumulates all 4 rows in one
// HTb pass (HT traffic /4).
__global__ __launch_bounds__(256) void k5_out(
    const float* __restrict__ P, const int* __restrict__ dep,
    const ushort* __restrict__ HTb, const float* __restrict__ bias,
    float* __restrict__ out) {
    int blk = blockIdx.x;
    int b = blk >> 5;
    int i0 = b * 128 + (blk & 31) * 4;
    int tid = threadIdx.x;
    int wr = tid >> 6, lane = tid & 63;
    __shared__ float a[4][NL];
    __shared__ float c0s[4];
    __shared__ float comb[4][48];
    __shared__ float invs[4];

    // phase A: c0[wr] = P1[row] . P2[row]  (one wave per row)
    {
        const float* p1 = P + (size_t)(i0 + wr) * NP + C_P1 + lane * 8;
        const float* p2 = P + (size_t)(i0 + wr) * NP + C_P2 + lane * 8;
        float4 x0 = *(const float4*)(p1);
        float4 x1 = *(const float4*)(p1 + 4);
        float4 y0 = *(const float4*)(p2);
        float4 y1 = *(const float4*)(p2 + 4);
        float s = x0.x * y0.x + x0.y * y0.y + x0.z * y0.z + x0.w * y0.w
                + x1.x * y1.x + x1.y * y1.y + x1.z * y1.z + x1.w * y1.w;
        for (int off = 32; off; off >>= 1) s += __shfl_down(s, off, 64);
        if (lane == 0) c0s[wr] = s;
    }
    // phase B: comb
    for (int idx = tid; idx < 4 * 45; idx += 256) {
        int r = idx / 45, t = idx - r * 45;
        const float* Prow = P + (size_t)(i0 + r) * NP;
        comb[r][t] = Prow[C_D1 + t] + Prow[C_D2 + t];
    }
    __syncthreads();

    // phase C: scores (unnormalized), 2 items/thread
#pragma unroll
    for (int k = 0; k < 2; k++) {
        int idx = tid + k * 256;
        int r = idx >> 7, j = idx & 127;
        int tt = dep[(size_t)(i0 + r) * NL + j];
        a[r][j] = (tt != 0) ? expf(c0s[r] + comb[r][tt]) : 0.f;
    }
    __syncthreads();
    // row sums: wave wr reduces row wr
    {
        float v = a[wr][lane] + a[wr][lane + 64];
        for (int off = 32; off; off >>= 1) v += __shfl_down(v, off, 64);
        if (lane == 0) invs[wr] = 1.0f / (v + 1e-6f);
    }
    __syncthreads();

    // phase D: thread owns cols o2, o2+1; accumulate 4 rows in one HT pass
    int o2 = tid * 2;
    float s00 = 0.f, s01 = 0.f, s10 = 0.f, s11 = 0.f;
    float s20 = 0.f, s21 = 0.f, s30 = 0.f, s31 = 0.f;
    const ushort* hp = HTb + (size_t)b * NL * 512 + o2;
#pragma unroll 8
    for (int j = 0; j < NL; j++) {
        ushort2 hv = *(const ushort2*)(hp + (size_t)j * 512);
        float h0 = bf2f(hv.x), h1 = bf2f(hv.y);
        float a0 = a[0][j], a1 = a[1][j], a2 = a[2][j], a3 = a[3][j];
        s00 += a0 * h0; s01 += a0 * h1;
        s10 += a1 * h0; s11 += a1 * h1;
        s20 += a2 * h0; s21 += a2 * h1;
        s30 += a3 * h0; s31 += a3 * h1;
    }
    float bv0 = bias[o2], bv1 = bias[o2 + 1];
    float i0v = invs[0], i1v = invs[1], i2v = invs[2], i3v = invs[3];
    float2 o;
    o.x = fmaxf(s00 * i0v + bv0, 0.f); o.y = fmaxf(s01 * i0v + bv1, 0.f);
    *(float2*)&out[(size_t)(i0 + 0) * 512 + o2] = o;
    o.x = fmaxf(s10 * i1v + bv0, 0.f); o.y = fmaxf(s11 * i1v + bv1, 0.f);
    *(float2*)&out[(size_t)(i0 + 1) * 512 + o2] = o;
    o.x = fmaxf(s20 * i2v + bv0, 0.f); o.y = fmaxf(s21 * i2v + bv1, 0.f);
    *(float2*)&out[(size_t)(i0 + 2) * 512 + o2] = o;
    o.x = fmaxf(s30 * i3v + bv0, 0.f); o.y = fmaxf(s31 * i3v + bv1, 0.f);
    *(float2*)&out[(size_t)(i0 + 3) * 512 + o2] = o;
}

extern "C" void kernel_launch(void* const* d_in, const int* in_sizes, int n_in,
                              void* d_out, int out_size, void* d_ws, size_t ws_size,
                              hipStream_t stream) {
    const float* h    = (const float*)d_in[0];
    const int* dep    = (const int*)d_in[1];
    const unsigned char* mask = (const unsigned char*)d_in[2];
    const float* emb  = (const float*)d_in[3];
    const float* W1   = (const float*)d_in[4];
    const float* b1   = (const float*)d_in[5];
    const float* W2   = (const float*)d_in[6];
    const float* b2   = (const float*)d_in[7];
    const float* Wg   = (const float*)d_in[8];
    const float* bg   = (const float*)d_in[9];
    const float* bias = (const float*)d_in[10];
    float* out = (float*)d_out;

    char* p = (char*)d_ws;
    ushort* A_hi = (ushort*)p;  p += (size_t)1024 * 512 * 2;   // 1 MB
    ushort* A_lo = (ushort*)p;  p += (size_t)1024 * 512 * 2;
    ushort* B_hi = (ushort*)p;  p += (size_t)NP * 512 * 2;     // 1.7 MB
    ushort* B_lo = (ushort*)p;  p += (size_t)NP * 512 * 2;
    ushort* HTb = (ushort*)p;   p += (size_t)1024 * 512 * 2;   // 1 MB
    float* bias_ext = (float*)p; p += NP * 4;
    float* Pout = (float*)p;    // 1024*1664*4 (HT region unused)

    k_prep<<<324, 256, 0, stream>>>(h, mask, emb, W1, W2, Wg, b1, b2, bg,
                                    A_hi, A_lo, B_hi, B_lo, bias_ext);
    dim3 g3(16, 26);
    k3_gemm<<<g3, 256, 0, stream>>>(A_hi, A_lo, B_hi, B_lo, bias_ext, Pout, HTb);
    k5_out<<<256, 256, 0, stream>>>(Pout, dep, HTb, bias, out);
}

// Round 15
// 53.625 us; speedup vs baseline: 1.3112x; 1.0189x over previous
//
#include <hip/hip_runtime.h>
#include <hip/hip_bf16.h>
#include <math.h>

#define NBATCH 8
#define NL 128
#define IND 512
#define DEPN 45
#define DEPD 16
#define WCOLS 528          // IN_DIM + DEP_DIM
#define NP 1664            // extended width (P1|P2|HT|D1|D2|pad)
#define C_P1 0
#define C_P2 512
#define C_HT 1024
#define C_D1 1536
#define C_D2 1581
#define C_PAD 1626

typedef __attribute__((ext_vector_type(8))) short bf16x8;
typedef __attribute__((ext_vector_type(4))) float f32x4;

__device__ inline ushort f2bf(float x) {
    __hip_bfloat16 b = __float2bfloat16(x);
    return *reinterpret_cast<ushort*>(&b);
}
__device__ inline float bf2f(ushort u) {
    __hip_bfloat16 b;
    *reinterpret_cast<ushort*>(&b) = u;
    return __bfloat162float(b);
}

__device__ __forceinline__ void gl16(const ushort* g, ushort* l) {
    __builtin_amdgcn_global_load_lds(
        (const __attribute__((address_space(1))) unsigned int*)g,
        (__attribute__((address_space(3))) unsigned int*)l, 16, 0, 0);
}

// ================= k_prep (unchanged from R14) =================
__global__ __launch_bounds__(256) void k_prep(
    const float* __restrict__ h, const unsigned char* __restrict__ mask,
    const float* __restrict__ emb,
    const float* __restrict__ W1, const float* __restrict__ W2,
    const float* __restrict__ Wg,
    const float* __restrict__ b1, const float* __restrict__ b2,
    const float* __restrict__ bg,
    ushort* __restrict__ A_hi, ushort* __restrict__ A_lo,
    ushort* __restrict__ B_hi, ushort* __restrict__ B_lo,
    float* __restrict__ bias_ext) {
    int bid = blockIdx.x;
    int tid = threadIdx.x;

    if (bid < 64) {
        int rb = bid * 16;
        int b = rb >> 7;
        __shared__ int sflag, smin, smax;
        __shared__ float w16[16];
        if (tid == 0) { sflag = 0; smin = NL; smax = -1; }
        __syncthreads();
        const int* mi = (const int*)mask;
        if (tid < 128) {
            int v0 = mi[tid], v1 = mi[tid + 128];
            if ((unsigned)v0 > 1u || (unsigned)v1 > 1u) atomicOr(&sflag, 1);
        }
        __syncthreads();
        if (tid < 128) {
            int mval = sflag ? (int)mask[b * NL + tid] : mi[b * NL + tid];
            if (mval) { atomicMin(&smin, tid); atomicMax(&smax, tid); }
        }
        __syncthreads();
        if (tid < 16) {
            int any = (smax >= 0);
            int s = any ? smin : 0;
            int e = any ? smax : (NL - 1);
            int i = (rb & 127) + tid;
            const float invL = 1.0f / (float)NL;
            float w;
            if (i < s)      w = 1.0f - (float)(s - i) * invL;
            else if (i > e) w = 1.0f - (float)(i - e) * invL;
            else            w = 0.0f;
            int mval = sflag ? (int)mask[b * NL + i] : mi[b * NL + i];
            if (mval) w = 0.0f;
            w16[tid] = w;
        }
        __syncthreads();
        for (int idx = tid; idx < 16 * 128; idx += 256) {
            int r = idx >> 7, dc = (idx & 127) << 2;
            float4 hv = *(const float4*)&h[(size_t)(rb + r) * IND + dc];
            float wv = w16[r];
            hv.x *= wv; hv.y *= wv; hv.z *= wv; hv.w *= wv;
            ushort4 hi4, lo4;
            hi4.x = f2bf(hv.x); hi4.y = f2bf(hv.y); hi4.z = f2bf(hv.z); hi4.w = f2bf(hv.w);
            lo4.x = f2bf(hv.x - bf2f(hi4.x));
            lo4.y = f2bf(hv.y - bf2f(hi4.y));
            lo4.z = f2bf(hv.z - bf2f(hi4.z));
            lo4.w = f2bf(hv.w - bf2f(hi4.w));
            *(ushort4*)&A_hi[(size_t)(rb + r) * IND + dc] = hi4;
            *(ushort4*)&A_lo[(size_t)(rb + r) * IND + dc] = lo4;
        }
        if (bid == 0) {
            for (int i = tid; i < 512; i += 256) {
                bias_ext[C_P1 + i] = b1[i];
                bias_ext[C_P2 + i] = b2[i];
                bias_ext[C_HT + i] = bg[i];
            }
            if (tid < NP - C_PAD) bias_ext[C_PAD + tid] = 0.f;
        }
    } else if (bid < 160) {
        int nb = (bid - 64) * 16;
        for (int idx = tid; idx < 16 * 128; idx += 256) {
            int r = idx >> 7, dc = (idx & 127) << 2;
            int n = nb + r;
            const float* src;
            if (n < 512)       src = W1 + (size_t)n * WCOLS + dc;
            else if (n < 1024) src = W2 + (size_t)(n - 512) * WCOLS + dc;
            else               src = Wg + (size_t)(n - 1024) * IND + dc;
            float4 wv = *(const float4*)src;
            ushort4 hi4, lo4;
            hi4.x = f2bf(wv.x); hi4.y = f2bf(wv.y); hi4.z = f2bf(wv.z); hi4.w = f2bf(wv.w);
            lo4.x = f2bf(wv.x - bf2f(hi4.x));
            lo4.y = f2bf(wv.y - bf2f(hi4.y));
            lo4.z = f2bf(wv.z - bf2f(hi4.z));
            lo4.w = f2bf(wv.w - bf2f(hi4.w));
            *(ushort4*)&B_hi[(size_t)n * IND + dc] = hi4;
            *(ushort4*)&B_lo[(size_t)n * IND + dc] = lo4;
        }
    } else if (bid < 162) {
        int nb = 1626 + (bid - 160) * 19;
        ushort4 z4 = {0, 0, 0, 0};
        for (int idx = tid; idx < 19 * 128; idx += 256) {
            int r = idx >> 7, dc = (idx & 127) << 2;
            *(ushort4*)&B_hi[(size_t)(nb + r) * IND + dc] = z4;
            *(ushort4*)&B_lo[(size_t)(nb + r) * IND + dc] = z4;
        }
    } else if (bid < 234) {
        int zi = bid - 162;               // 0..71
        int m = zi / 36;
        int rest = zi % 36;
        int dq = rest / 9;
        int tq = rest % 9;
        int tb = tq * 5;
        __shared__ float es5[5][DEPD];
        __shared__ float ys5[5][512];
        __shared__ float part[5][256];
        if (tid < 5 * DEPD) es5[tid >> 4][tid & 15] = emb[(tb + (tid >> 4)) * DEPD + (tid & 15)];
        __syncthreads();
        const float* Wdep = (m == 0) ? W2 : W1;
        for (int idx = tid; idx < 5 * 512; idx += 256) {
            int tt = idx >> 9, o = idx & 511;
            float s = 0.f;
#pragma unroll
            for (int e = 0; e < DEPD; e++) s += es5[tt][e] * Wdep[o * WCOLS + IND + e];
            ys5[tt][o] = s;
        }
        __syncthreads();
        int dloc = tid & 127, half = tid >> 7;
        const float* Wsrc = (m == 0) ? W1 : W2;
        int d = dq * 128 + dloc;
        int obase = half * 256;
        float ac0 = 0.f, ac1 = 0.f, ac2 = 0.f, ac3 = 0.f, ac4 = 0.f;
#pragma unroll 8
        for (int oo = 0; oo < 256; oo++) {
            float w = Wsrc[(size_t)(obase + oo) * WCOLS + d];
            int o = obase + oo;
            ac0 += w * ys5[0][o];
            ac1 += w * ys5[1][o];
            ac2 += w * ys5[2][o];
            ac3 += w * ys5[3][o];
            ac4 += w * ys5[4][o];
        }
        part[0][tid] = ac0; part[1][tid] = ac1; part[2][tid] = ac2;
        part[3][tid] = ac3; part[4][tid] = ac4;
        __syncthreads();
        if (half == 0) {
#pragma unroll
            for (int tt = 0; tt < 5; tt++) {
                float tot = part[tt][dloc] + part[tt][128 + dloc];
                int row = ((m == 0) ? C_D1 : C_D2) + tb + tt;
                ushort hi = f2bf(tot);
                B_hi[(size_t)row * IND + d] = hi;
                B_lo[(size_t)row * IND + d] = f2bf(tot - bf2f(hi));
            }
        }
    } else {
        int zi2 = bid - 234;              // 0..89
        int t = zi2 % 45;
        int m = zi2 / 45;
        __shared__ float es[DEPD];
        __shared__ float ys[512];
        __shared__ float y1s[512];
        if (tid < DEPD) es[tid] = emb[t * DEPD + tid];
        __syncthreads();
        const float* Wdep = (m == 0) ? W2 : W1;
        for (int o = tid; o < 512; o += 256) {
            float s = 0.f;
#pragma unroll
            for (int e = 0; e < DEPD; e++) s += es[e] * Wdep[o * WCOLS + IND + e];
            ys[o] = s;
        }
        if (m == 0) {
            for (int o = tid; o < 512; o += 256) {
                float s = 0.f;
#pragma unroll
                for (int e = 0; e < DEPD; e++) s += es[e] * W1[o * WCOLS + IND + e];
                y1s[o] = s;
            }
        }
        __syncthreads();
        if (tid < 64) {
            const float* bb = (m == 0) ? b1 : b2;
            float sb = 0.f;
#pragma unroll
            for (int k = 0; k < 8; k++) sb += bb[tid + k * 64] * ys[tid + k * 64];
            if (m == 0) {
#pragma unroll
                for (int k = 0; k < 8; k++) sb += y1s[tid + k * 64] * ys[tid + k * 64];
            }
            for (int off = 32; off; off >>= 1) sb += __shfl_down(sb, off, 64);
            if (tid == 0) bias_ext[((m == 0) ? C_D1 : C_D2) + t] = sb;
        }
    }
}

// ================= k3: LDS-shared MFMA GEMM, 64x64 tile, double-buffered =================
// Grid (16, 26) = 416 blocks; 256 thr = 4 waves (2m x 2n wave grid, 32x32 each).
// K-chunk 64; wave w stages one of {Ah, Al, Bh, Bl} via global_load_lds.
// Double-buffered LDS (64 KB -> 2 blocks/CU): next chunk's loads issue right
// after the barrier and fly under the MFMA phase; the NEXT barrier's implicit
// vmcnt(0) drain publishes them (m97 pattern).
__global__ __launch_bounds__(256) void k3_gemm(
    const ushort* __restrict__ A_hi, const ushort* __restrict__ A_lo,
    const ushort* __restrict__ B_hi, const ushort* __restrict__ B_lo,
    const float* __restrict__ bias_ext, float* __restrict__ Pout,
    ushort* __restrict__ HTb) {
    int tid = threadIdx.x;
    int wid = tid >> 6, lane = tid & 63;
    int lrow = lane & 15;
    int mbase = blockIdx.x * 64;
    int nbase = blockIdx.y * 64;
    int mh = (wid >> 1) << 5;
    int nh = (wid & 1) << 5;

    __shared__ ushort Ah[2][8 * 64 * 8];   // 8 KB per buffer per array
    __shared__ ushort Al[2][8 * 64 * 8];
    __shared__ ushort Bh[2][8 * 64 * 8];
    __shared__ ushort Bl[2][8 * 64 * 8];

    const ushort* aH = A_hi + (size_t)(mbase + lane) * IND;
    const ushort* aL = A_lo + (size_t)(mbase + lane) * IND;
    const ushort* bH = B_hi + (size_t)(nbase + lane) * IND;
    const ushort* bL = B_lo + (size_t)(nbase + lane) * IND;

#define STAGE(BUF, C) { \
    int ck = (C) << 6; \
    if (wid == 0) { \
        _Pragma("unroll") \
        for (int g = 0; g < 8; g++) gl16(aH + ck + (g << 3), &Ah[BUF][g << 9]); \
    } else if (wid == 1) { \
        _Pragma("unroll") \
        for (int g = 0; g < 8; g++) gl16(aL + ck + (g << 3), &Al[BUF][g << 9]); \
    } else if (wid == 2) { \
        _Pragma("unroll") \
        for (int g = 0; g < 8; g++) gl16(bH + ck + (g << 3), &Bh[BUF][g << 9]); \
    } else { \
        _Pragma("unroll") \
        for (int g = 0; g < 8; g++) gl16(bL + ck + (g << 3), &Bl[BUF][g << 9]); \
    } }

    f32x4 acc00 = {0.f, 0.f, 0.f, 0.f};
    f32x4 acc01 = acc00, acc10 = acc00, acc11 = acc00;

    STAGE(0, 0)
    for (int c = 0; c < 8; c++) {
        int cb = c & 1;
        __syncthreads();   // implicit vmcnt(0): buf[cb] staged; prev readers of buf[cb^1] done
        if (c < 7) STAGE(cb ^ 1, c + 1)   // in flight during compute below
#pragma unroll
        for (int KS = 0; KS < 2; KS++) {
            int gA = (KS << 2) + (lane >> 4);
            int ga = ((gA << 6) + mh + lrow) << 3;
            int gb = ((gA << 6) + nh + lrow) << 3;
            bf16x8 a0h = *(const bf16x8*)&Ah[cb][ga];
            bf16x8 a0l = *(const bf16x8*)&Al[cb][ga];
            bf16x8 a1h = *(const bf16x8*)&Ah[cb][ga + 128];
            bf16x8 a1l = *(const bf16x8*)&Al[cb][ga + 128];
            bf16x8 b0h = *(const bf16x8*)&Bh[cb][gb];
            bf16x8 b0l = *(const bf16x8*)&Bl[cb][gb];
            bf16x8 b1h = *(const bf16x8*)&Bh[cb][gb + 128];
            bf16x8 b1l = *(const bf16x8*)&Bl[cb][gb + 128];
            acc00 = __builtin_amdgcn_mfma_f32_16x16x32_bf16(a0h, b0h, acc00, 0, 0, 0);
            acc00 = __builtin_amdgcn_mfma_f32_16x16x32_bf16(a0h, b0l, acc00, 0, 0, 0);
            acc00 = __builtin_amdgcn_mfma_f32_16x16x32_bf16(a0l, b0h, acc00, 0, 0, 0);
            acc01 = __builtin_amdgcn_mfma_f32_16x16x32_bf16(a0h, b1h, acc01, 0, 0, 0);
            acc01 = __builtin_amdgcn_mfma_f32_16x16x32_bf16(a0h, b1l, acc01, 0, 0, 0);
            acc01 = __builtin_amdgcn_mfma_f32_16x16x32_bf16(a0l, b1h, acc01, 0, 0, 0);
            acc10 = __builtin_amdgcn_mfma_f32_16x16x32_bf16(a1h, b0h, acc10, 0, 0, 0);
            acc10 = __builtin_amdgcn_mfma_f32_16x16x32_bf16(a1h, b0l, acc10, 0, 0, 0);
            acc10 = __builtin_amdgcn_mfma_f32_16x16x32_bf16(a1l, b0h, acc10, 0, 0, 0);
            acc11 = __builtin_amdgcn_mfma_f32_16x16x32_bf16(a1h, b1h, acc11, 0, 0, 0);
            acc11 = __builtin_amdgcn_mfma_f32_16x16x32_bf16(a1h, b1l, acc11, 0, 0, 0);
            acc11 = __builtin_amdgcn_mfma_f32_16x16x32_bf16(a1l, b1h, acc11, 0, 0, 0);
        }
    }
#undef STAGE

    int r0 = (lane >> 4) << 2;
    int colb = nbase + nh;
    int col0 = colb + lrow;
    int col1 = col0 + 16;
    float bv0 = bias_ext[col0];
    float bv1 = bias_ext[col1];
    int rowb = mbase + mh;

    if (colb >= C_HT && colb < C_HT + 512) {
        int o0 = col0 - C_HT, o1 = col1 - C_HT;
#pragma unroll
        for (int r = 0; r < 4; ++r) {
            int row0 = rowb + r0 + r;
            int row1 = row0 + 16;
            HTb[(size_t)row0 * 512 + o0] = f2bf(acc00[r] + bv0);
            HTb[(size_t)row0 * 512 + o1] = f2bf(acc01[r] + bv1);
            HTb[(size_t)row1 * 512 + o0] = f2bf(acc10[r] + bv0);
            HTb[(size_t)row1 * 512 + o1] = f2bf(acc11[r] + bv1);
        }
    } else {
#pragma unroll
        for (int r = 0; r < 4; ++r) {
            int row0 = rowb + r0 + r;
            int row1 = row0 + 16;
            Pout[(size_t)row0 * NP + col0] = acc00[r] + bv0;
            Pout[(size_t)row0 * NP + col1] = acc01[r] + bv1;
            Pout[(size_t)row1 * NP + col0] = acc10[r] + bv0;
            Pout[(size_t)row1 * NP + col1] = acc11[r] + bv1;
        }
    }
}

// ================= k5: 4 rows/block; softmax + shared-HT matmul (R14) =================
__global__ __launch_bounds__(256) void k5_out(
    const float* __restrict__ P, const int* __restrict__ dep,
    const ushort* __restrict__ HTb, const float* __restrict__ bias,
    float* __restrict__ out) {
    int blk = blockIdx.x;
    int b = blk >> 5;
    int i0 = b * 128 + (blk & 31) * 4;
    int tid = threadIdx.x;
    int wr = tid >> 6, lane = tid & 63;
    __shared__ float a[4][NL];
    __shared__ float c0s[4];
    __shared__ float comb[4][48];
    __shared__ float invs[4];

    {
        const float* p1 = P + (size_t)(i0 + wr) * NP + C_P1 + lane * 8;
        const float* p2 = P + (size_t)(i0 + wr) * NP + C_P2 + lane * 8;
        float4 x0 = *(const float4*)(p1);
        float4 x1 = *(const float4*)(p1 + 4);
        float4 y0 = *(const float4*)(p2);
        float4 y1 = *(const float4*)(p2 + 4);
        float s = x0.x * y0.x + x0.y * y0.y + x0.z * y0.z + x0.w * y0.w
                + x1.x * y1.x + x1.y * y1.y + x1.z * y1.z + x1.w * y1.w;
        for (int off = 32; off; off >>= 1) s += __shfl_down(s, off, 64);
        if (lane == 0) c0s[wr] = s;
    }
    for (int idx = tid; idx < 4 * 45; idx += 256) {
        int r = idx / 45, t = idx - r * 45;
        const float* Prow = P + (size_t)(i0 + r) * NP;
        comb[r][t] = Prow[C_D1 + t] + Prow[C_D2 + t];
    }
    __syncthreads();

#pragma unroll
    for (int k = 0; k < 2; k++) {
        int idx = tid + k * 256;
        int r = idx >> 7, j = idx & 127;
        int tt = dep[(size_t)(i0 + r) * NL + j];
        a[r][j] = (tt != 0) ? expf(c0s[r] + comb[r][tt]) : 0.f;
    }
    __syncthreads();
    {
        float v = a[wr][lane] + a[wr][lane + 64];
        for (int off = 32; off; off >>= 1) v += __shfl_down(v, off, 64);
        if (lane == 0) invs[wr] = 1.0f / (v + 1e-6f);
    }
    __syncthreads();

    int o2 = tid * 2;
    float s00 = 0.f, s01 = 0.f, s10 = 0.f, s11 = 0.f;
    float s20 = 0.f, s21 = 0.f, s30 = 0.f, s31 = 0.f;
    const ushort* hp = HTb + (size_t)b * NL * 512 + o2;
#pragma unroll 8
    for (int j = 0; j < NL; j++) {
        ushort2 hv = *(const ushort2*)(hp + (size_t)j * 512);
        float h0 = bf2f(hv.x), h1 = bf2f(hv.y);
        float a0 = a[0][j], a1 = a[1][j], a2 = a[2][j], a3 = a[3][j];
        s00 += a0 * h0; s01 += a0 * h1;
        s10 += a1 * h0; s11 += a1 * h1;
        s20 += a2 * h0; s21 += a2 * h1;
        s30 += a3 * h0; s31 += a3 * h1;
    }
    float bv0 = bias[o2], bv1 = bias[o2 + 1];
    float i0v = invs[0], i1v = invs[1], i2v = invs[2], i3v = invs[3];
    float2 o;
    o.x = fmaxf(s00 * i0v + bv0, 0.f); o.y = fmaxf(s01 * i0v + bv1, 0.f);
    *(float2*)&out[(size_t)(i0 + 0) * 512 + o2] = o;
    o.x = fmaxf(s10 * i1v + bv0, 0.f); o.y = fmaxf(s11 * i1v + bv1, 0.f);
    *(float2*)&out[(size_t)(i0 + 1) * 512 + o2] = o;
    o.x = fmaxf(s20 * i2v + bv0, 0.f); o.y = fmaxf(s21 * i2v + bv1, 0.f);
    *(float2*)&out[(size_t)(i0 + 2) * 512 + o2] = o;
    o.x = fmaxf(s30 * i3v + bv0, 0.f); o.y = fmaxf(s31 * i3v + bv1, 0.f);
    *(float2*)&out[(size_t)(i0 + 3) * 512 + o2] = o;
}

extern "C" void kernel_launch(void* const* d_in, const int* in_sizes, int n_in,
                              void* d_out, int out_size, void* d_ws, size_t ws_size,
                              hipStream_t stream) {
    const float* h    = (const float*)d_in[0];
    const int* dep    = (const int*)d_in[1];
    const unsigned char* mask = (const unsigned char*)d_in[2];
    const float* emb  = (const float*)d_in[3];
    const float* W1   = (const float*)d_in[4];
    const float* b1   = (const float*)d_in[5];
    const float* W2   = (const float*)d_in[6];
    const float* b2   = (const float*)d_in[7];
    const float* Wg   = (const float*)d_in[8];
    const float* bg   = (const float*)d_in[9];
    const float* bias = (const float*)d_in[10];
    float* out = (float*)d_out;

    char* p = (char*)d_ws;
    ushort* A_hi = (ushort*)p;  p += (size_t)1024 * 512 * 2;   // 1 MB
    ushort* A_lo = (ushort*)p;  p += (size_t)1024 * 512 * 2;
    ushort* B_hi = (ushort*)p;  p += (size_t)NP * 512 * 2;     // 1.7 MB
    ushort* B_lo = (ushort*)p;  p += (size_t)NP * 512 * 2;
    ushort* HTb = (ushort*)p;   p += (size_t)1024 * 512 * 2;   // 1 MB
    float* bias_ext = (float*)p; p += NP * 4;
    float* Pout = (float*)p;    // 1024*1664*4 (HT region unused)

    k_prep<<<324, 256, 0, stream>>>(h, mask, emb, W1, W2, Wg, b1, b2, bg,
                                    A_hi, A_lo, B_hi, B_lo, bias_ext);
    dim3 g3(16, 26);
    k3_gemm<<<g3, 256, 0, stream>>>(A_hi, A_lo, B_hi, B_lo, bias_ext, Pout, HTb);
    k5_out<<<256, 256, 0, stream>>>(Pout, dep, HTb, bias, out);
}

// Round 16
// 48.090 us; speedup vs baseline: 1.4622x; 1.1151x over previous
//
#include <hip/hip_runtime.h>
#include <hip/hip_bf16.h>
#include <math.h>

#define NBATCH 8
#define NL 128
#define IND 512
#define DEPN 45
#define DEPD 16
#define WCOLS 528          // IN_DIM + DEP_DIM
#define NP 1664            // extended width (P1|P2|HT|D1|D2|pad)
#define C_P1 0
#define C_P2 512
#define C_HT 1024
#define C_D1 1536
#define C_D2 1581
#define C_PAD 1626

typedef __attribute__((ext_vector_type(8))) short bf16x8;
typedef __attribute__((ext_vector_type(4))) float f32x4;

__device__ inline ushort f2bf(float x) {
    __hip_bfloat16 b = __float2bfloat16(x);
    return *reinterpret_cast<ushort*>(&b);
}
__device__ inline float bf2f(ushort u) {
    __hip_bfloat16 b;
    *reinterpret_cast<ushort*>(&b) = u;
    return __bfloat162float(b);
}

__device__ __forceinline__ void gl16(const ushort* g, ushort* l) {
    __builtin_amdgcn_global_load_lds(
        (const __attribute__((address_space(1))) unsigned int*)g,
        (__attribute__((address_space(3))) unsigned int*)l, 16, 0, 0);
}

// ================= k_prep (R14 structure; B_lo skipped for rows<1024) =================
__global__ __launch_bounds__(256) void k_prep(
    const float* __restrict__ h, const unsigned char* __restrict__ mask,
    const float* __restrict__ emb,
    const float* __restrict__ W1, const float* __restrict__ W2,
    const float* __restrict__ Wg,
    const float* __restrict__ b1, const float* __restrict__ b2,
    const float* __restrict__ bg,
    ushort* __restrict__ A_hi, ushort* __restrict__ A_lo,
    ushort* __restrict__ B_hi, ushort* __restrict__ B_lo,
    float* __restrict__ bias_ext) {
    int bid = blockIdx.x;
    int tid = threadIdx.x;

    if (bid < 64) {
        int rb = bid * 16;
        int b = rb >> 7;
        __shared__ int sflag, smin, smax;
        __shared__ float w16[16];
        if (tid == 0) { sflag = 0; smin = NL; smax = -1; }
        __syncthreads();
        const int* mi = (const int*)mask;
        if (tid < 128) {
            int v0 = mi[tid], v1 = mi[tid + 128];
            if ((unsigned)v0 > 1u || (unsigned)v1 > 1u) atomicOr(&sflag, 1);
        }
        __syncthreads();
        if (tid < 128) {
            int mval = sflag ? (int)mask[b * NL + tid] : mi[b * NL + tid];
            if (mval) { atomicMin(&smin, tid); atomicMax(&smax, tid); }
        }
        __syncthreads();
        if (tid < 16) {
            int any = (smax >= 0);
            int s = any ? smin : 0;
            int e = any ? smax : (NL - 1);
            int i = (rb & 127) + tid;
            const float invL = 1.0f / (float)NL;
            float w;
            if (i < s)      w = 1.0f - (float)(s - i) * invL;
            else if (i > e) w = 1.0f - (float)(i - e) * invL;
            else            w = 0.0f;
            int mval = sflag ? (int)mask[b * NL + i] : mi[b * NL + i];
            if (mval) w = 0.0f;
            w16[tid] = w;
        }
        __syncthreads();
        for (int idx = tid; idx < 16 * 128; idx += 256) {
            int r = idx >> 7, dc = (idx & 127) << 2;
            float4 hv = *(const float4*)&h[(size_t)(rb + r) * IND + dc];
            float wv = w16[r];
            hv.x *= wv; hv.y *= wv; hv.z *= wv; hv.w *= wv;
            ushort4 hi4, lo4;
            hi4.x = f2bf(hv.x); hi4.y = f2bf(hv.y); hi4.z = f2bf(hv.z); hi4.w = f2bf(hv.w);
            lo4.x = f2bf(hv.x - bf2f(hi4.x));
            lo4.y = f2bf(hv.y - bf2f(hi4.y));
            lo4.z = f2bf(hv.z - bf2f(hi4.z));
            lo4.w = f2bf(hv.w - bf2f(hi4.w));
            *(ushort4*)&A_hi[(size_t)(rb + r) * IND + dc] = hi4;
            *(ushort4*)&A_lo[(size_t)(rb + r) * IND + dc] = lo4;
        }
        if (bid == 0) {
            for (int i = tid; i < 512; i += 256) {
                bias_ext[C_P1 + i] = b1[i];
                bias_ext[C_P2 + i] = b2[i];
                bias_ext[C_HT + i] = bg[i];
            }
            if (tid < NP - C_PAD) bias_ext[C_PAD + tid] = 0.f;
        }
    } else if (bid < 160) {
        int nb = (bid - 64) * 16;
        for (int idx = tid; idx < 16 * 128; idx += 256) {
            int r = idx >> 7, dc = (idx & 127) << 2;
            int n = nb + r;
            const float* src;
            if (n < 512)       src = W1 + (size_t)n * WCOLS + dc;
            else if (n < 1024) src = W2 + (size_t)(n - 512) * WCOLS + dc;
            else               src = Wg + (size_t)(n - 1024) * IND + dc;
            float4 wv = *(const float4*)src;
            ushort4 hi4;
            hi4.x = f2bf(wv.x); hi4.y = f2bf(wv.y); hi4.z = f2bf(wv.z); hi4.w = f2bf(wv.w);
            *(ushort4*)&B_hi[(size_t)n * IND + dc] = hi4;
            if (n >= 1024) {   // lo only needed for HT/D chunks (3-term region)
                ushort4 lo4;
                lo4.x = f2bf(wv.x - bf2f(hi4.x));
                lo4.y = f2bf(wv.y - bf2f(hi4.y));
                lo4.z = f2bf(wv.z - bf2f(hi4.z));
                lo4.w = f2bf(wv.w - bf2f(hi4.w));
                *(ushort4*)&B_lo[(size_t)n * IND + dc] = lo4;
            }
        }
    } else if (bid < 162) {
        int nb = 1626 + (bid - 160) * 19;
        ushort4 z4 = {0, 0, 0, 0};
        for (int idx = tid; idx < 19 * 128; idx += 256) {
            int r = idx >> 7, dc = (idx & 127) << 2;
            *(ushort4*)&B_hi[(size_t)(nb + r) * IND + dc] = z4;
            *(ushort4*)&B_lo[(size_t)(nb + r) * IND + dc] = z4;
        }
    } else if (bid < 234) {
        int zi = bid - 162;               // 0..71
        int m = zi / 36;
        int rest = zi % 36;
        int dq = rest / 9;
        int tq = rest % 9;
        int tb = tq * 5;
        __shared__ float es5[5][DEPD];
        __shared__ float ys5[5][512];
        __shared__ float part[5][256];
        if (tid < 5 * DEPD) es5[tid >> 4][tid & 15] = emb[(tb + (tid >> 4)) * DEPD + (tid & 15)];
        __syncthreads();
        const float* Wdep = (m == 0) ? W2 : W1;
        for (int idx = tid; idx < 5 * 512; idx += 256) {
            int tt = idx >> 9, o = idx & 511;
            float s = 0.f;
#pragma unroll
            for (int e = 0; e < DEPD; e++) s += es5[tt][e] * Wdep[o * WCOLS + IND + e];
            ys5[tt][o] = s;
        }
        __syncthreads();
        int dloc = tid & 127, half = tid >> 7;
        const float* Wsrc = (m == 0) ? W1 : W2;
        int d = dq * 128 + dloc;
        int obase = half * 256;
        float ac0 = 0.f, ac1 = 0.f, ac2 = 0.f, ac3 = 0.f, ac4 = 0.f;
#pragma unroll 8
        for (int oo = 0; oo < 256; oo++) {
            float w = Wsrc[(size_t)(obase + oo) * WCOLS + d];
            int o = obase + oo;
            ac0 += w * ys5[0][o];
            ac1 += w * ys5[1][o];
            ac2 += w * ys5[2][o];
            ac3 += w * ys5[3][o];
            ac4 += w * ys5[4][o];
        }
        part[0][tid] = ac0; part[1][tid] = ac1; part[2][tid] = ac2;
        part[3][tid] = ac3; part[4][tid] = ac4;
        __syncthreads();
        if (half == 0) {
#pragma unroll
            for (int tt = 0; tt < 5; tt++) {
                float tot = part[tt][dloc] + part[tt][128 + dloc];
                int row = ((m == 0) ? C_D1 : C_D2) + tb + tt;
                ushort hi = f2bf(tot);
                B_hi[(size_t)row * IND + d] = hi;
                B_lo[(size_t)row * IND + d] = f2bf(tot - bf2f(hi));
            }
        }
    } else {
        int zi2 = bid - 234;              // 0..89
        int t = zi2 % 45;
        int m = zi2 / 45;
        __shared__ float es[DEPD];
        __shared__ float ys[512];
        __shared__ float y1s[512];
        if (tid < DEPD) es[tid] = emb[t * DEPD + tid];
        __syncthreads();
        const float* Wdep = (m == 0) ? W2 : W1;
        for (int o = tid; o < 512; o += 256) {
            float s = 0.f;
#pragma unroll
            for (int e = 0; e < DEPD; e++) s += es[e] * Wdep[o * WCOLS + IND + e];
            ys[o] = s;
        }
        if (m == 0) {
            for (int o = tid; o < 512; o += 256) {
                float s = 0.f;
#pragma unroll
                for (int e = 0; e < DEPD; e++) s += es[e] * W1[o * WCOLS + IND + e];
                y1s[o] = s;
            }
        }
        __syncthreads();
        if (tid < 64) {
            const float* bb = (m == 0) ? b1 : b2;
            float sb = 0.f;
#pragma unroll
            for (int k = 0; k < 8; k++) sb += bb[tid + k * 64] * ys[tid + k * 64];
            if (m == 0) {
#pragma unroll
                for (int k = 0; k < 8; k++) sb += y1s[tid + k * 64] * ys[tid + k * 64];
            }
            for (int off = 32; off; off >>= 1) sb += __shfl_down(sb, off, 64);
            if (tid == 0) bias_ext[((m == 0) ? C_D1 : C_D2) + t] = sb;
        }
    }
}

// ================= k3: precision-tiered, double-buffered MFMA GEMM =================
// Grid (16, 26), 256 thr = 4 waves (2m x 2n wave grid, 32x32 each), 64x64 tile.
// n-chunks < C_HT (P1/P2): 1-term Ah.Bh (c0 is per-row constant -> cancels in
// softmax normalization; bf16 precision suffices). n-chunks >= C_HT (HT|D):
// full 3-term hi/lo. Double-buffered LDS, global_load_lds staging.
__global__ __launch_bounds__(256) void k3_gemm(
    const ushort* __restrict__ A_hi, const ushort* __restrict__ A_lo,
    const ushort* __restrict__ B_hi, const ushort* __restrict__ B_lo,
    const float* __restrict__ bias_ext, float* __restrict__ Pout,
    ushort* __restrict__ HTb) {
    int tid = threadIdx.x;
    int wid = tid >> 6, lane = tid & 63;
    int lrow = lane & 15;
    int mbase = blockIdx.x * 64;
    int nbase = blockIdx.y * 64;
    int mh = (wid >> 1) << 5;
    int nh = (wid & 1) << 5;

    __shared__ ushort Ah[2][8 * 64 * 8];
    __shared__ ushort Al[2][8 * 64 * 8];
    __shared__ ushort Bh[2][8 * 64 * 8];
    __shared__ ushort Bl[2][8 * 64 * 8];

    const ushort* aH = A_hi + (size_t)(mbase + lane) * IND;
    const ushort* aL = A_lo + (size_t)(mbase + lane) * IND;
    const ushort* bH = B_hi + (size_t)(nbase + lane) * IND;
    const ushort* bL = B_lo + (size_t)(nbase + lane) * IND;

    f32x4 acc00 = {0.f, 0.f, 0.f, 0.f};
    f32x4 acc01 = acc00, acc10 = acc00, acc11 = acc00;

    if (nbase >= C_HT) {
        // ---------- full 3-term path (HT | D1 | D2 | pad) ----------
#define STAGE(BUF, C) { \
    int ck = (C) << 6; \
    if (wid == 0) { \
        _Pragma("unroll") \
        for (int g = 0; g < 8; g++) gl16(aH + ck + (g << 3), &Ah[BUF][g << 9]); \
    } else if (wid == 1) { \
        _Pragma("unroll") \
        for (int g = 0; g < 8; g++) gl16(aL + ck + (g << 3), &Al[BUF][g << 9]); \
    } else if (wid == 2) { \
        _Pragma("unroll") \
        for (int g = 0; g < 8; g++) gl16(bH + ck + (g << 3), &Bh[BUF][g << 9]); \
    } else { \
        _Pragma("unroll") \
        for (int g = 0; g < 8; g++) gl16(bL + ck + (g << 3), &Bl[BUF][g << 9]); \
    } }
        STAGE(0, 0)
        for (int c = 0; c < 8; c++) {
            int cb = c & 1;
            __syncthreads();
            if (c < 7) STAGE(cb ^ 1, c + 1)
#pragma unroll
            for (int KS = 0; KS < 2; KS++) {
                int gA = (KS << 2) + (lane >> 4);
                int ga = ((gA << 6) + mh + lrow) << 3;
                int gb = ((gA << 6) + nh + lrow) << 3;
                bf16x8 a0h = *(const bf16x8*)&Ah[cb][ga];
                bf16x8 a0l = *(const bf16x8*)&Al[cb][ga];
                bf16x8 a1h = *(const bf16x8*)&Ah[cb][ga + 128];
                bf16x8 a1l = *(const bf16x8*)&Al[cb][ga + 128];
                bf16x8 b0h = *(const bf16x8*)&Bh[cb][gb];
                bf16x8 b0l = *(const bf16x8*)&Bl[cb][gb];
                bf16x8 b1h = *(const bf16x8*)&Bh[cb][gb + 128];
                bf16x8 b1l = *(const bf16x8*)&Bl[cb][gb + 128];
                acc00 = __builtin_amdgcn_mfma_f32_16x16x32_bf16(a0h, b0h, acc00, 0, 0, 0);
                acc00 = __builtin_amdgcn_mfma_f32_16x16x32_bf16(a0h, b0l, acc00, 0, 0, 0);
                acc00 = __builtin_amdgcn_mfma_f32_16x16x32_bf16(a0l, b0h, acc00, 0, 0, 0);
                acc01 = __builtin_amdgcn_mfma_f32_16x16x32_bf16(a0h, b1h, acc01, 0, 0, 0);
                acc01 = __builtin_amdgcn_mfma_f32_16x16x32_bf16(a0h, b1l, acc01, 0, 0, 0);
                acc01 = __builtin_amdgcn_mfma_f32_16x16x32_bf16(a0l, b1h, acc01, 0, 0, 0);
                acc10 = __builtin_amdgcn_mfma_f32_16x16x32_bf16(a1h, b0h, acc10, 0, 0, 0);
                acc10 = __builtin_amdgcn_mfma_f32_16x16x32_bf16(a1h, b0l, acc10, 0, 0, 0);
                acc10 = __builtin_amdgcn_mfma_f32_16x16x32_bf16(a1l, b0h, acc10, 0, 0, 0);
                acc11 = __builtin_amdgcn_mfma_f32_16x16x32_bf16(a1h, b1h, acc11, 0, 0, 0);
                acc11 = __builtin_amdgcn_mfma_f32_16x16x32_bf16(a1h, b1l, acc11, 0, 0, 0);
                acc11 = __builtin_amdgcn_mfma_f32_16x16x32_bf16(a1l, b1h, acc11, 0, 0, 0);
            }
        }
#undef STAGE
    } else {
        // ---------- light 1-term path (P1 | P2): Ah.Bh only ----------
#define STAGEL(BUF, C) { \
    int ck = (C) << 6; \
    if (wid == 0) { \
        _Pragma("unroll") \
        for (int g = 0; g < 4; g++) gl16(aH + ck + (g << 3), &Ah[BUF][g << 9]); \
    } else if (wid == 1) { \
        _Pragma("unroll") \
        for (int g = 4; g < 8; g++) gl16(aH + ck + (g << 3), &Ah[BUF][g << 9]); \
    } else if (wid == 2) { \
        _Pragma("unroll") \
        for (int g = 0; g < 4; g++) gl16(bH + ck + (g << 3), &Bh[BUF][g << 9]); \
    } else { \
        _Pragma("unroll") \
        for (int g = 4; g < 8; g++) gl16(bH + ck + (g << 3), &Bh[BUF][g << 9]); \
    } }
        STAGEL(0, 0)
        for (int c = 0; c < 8; c++) {
            int cb = c & 1;
            __syncthreads();
            if (c < 7) STAGEL(cb ^ 1, c + 1)
#pragma unroll
            for (int KS = 0; KS < 2; KS++) {
                int gA = (KS << 2) + (lane >> 4);
                int ga = ((gA << 6) + mh + lrow) << 3;
                int gb = ((gA << 6) + nh + lrow) << 3;
                bf16x8 a0h = *(const bf16x8*)&Ah[cb][ga];
                bf16x8 a1h = *(const bf16x8*)&Ah[cb][ga + 128];
                bf16x8 b0h = *(const bf16x8*)&Bh[cb][gb];
                bf16x8 b1h = *(const bf16x8*)&Bh[cb][gb + 128];
                acc00 = __builtin_amdgcn_mfma_f32_16x16x32_bf16(a0h, b0h, acc00, 0, 0, 0);
                acc01 = __builtin_amdgcn_mfma_f32_16x16x32_bf16(a0h, b1h, acc01, 0, 0, 0);
                acc10 = __builtin_amdgcn_mfma_f32_16x16x32_bf16(a1h, b0h, acc10, 0, 0, 0);
                acc11 = __builtin_amdgcn_mfma_f32_16x16x32_bf16(a1h, b1h, acc11, 0, 0, 0);
            }
        }
#undef STAGEL
    }

    int r0 = (lane >> 4) << 2;
    int colb = nbase + nh;
    int col0 = colb + lrow;
    int col1 = col0 + 16;
    float bv0 = bias_ext[col0];
    float bv1 = bias_ext[col1];
    int rowb = mbase + mh;

    if (colb >= C_HT && colb < C_HT + 512) {
        int o0 = col0 - C_HT, o1 = col1 - C_HT;
#pragma unroll
        for (int r = 0; r < 4; ++r) {
            int row0 = rowb + r0 + r;
            int row1 = row0 + 16;
            HTb[(size_t)row0 * 512 + o0] = f2bf(acc00[r] + bv0);
            HTb[(size_t)row0 * 512 + o1] = f2bf(acc01[r] + bv1);
            HTb[(size_t)row1 * 512 + o0] = f2bf(acc10[r] + bv0);
            HTb[(size_t)row1 * 512 + o1] = f2bf(acc11[r] + bv1);
        }
    } else {
#pragma unroll
        for (int r = 0; r < 4; ++r) {
            int row0 = rowb + r0 + r;
            int row1 = row0 + 16;
            Pout[(size_t)row0 * NP + col0] = acc00[r] + bv0;
            Pout[(size_t)row0 * NP + col1] = acc01[r] + bv1;
            Pout[(size_t)row1 * NP + col0] = acc10[r] + bv0;
            Pout[(size_t)row1 * NP + col1] = acc11[r] + bv1;
        }
    }
}

// ================= k5: 4 rows/block; softmax + shared-HT matmul (R14) =================
__global__ __launch_bounds__(256) void k5_out(
    const float* __restrict__ P, const int* __restrict__ dep,
    const ushort* __restrict__ HTb, const float* __restrict__ bias,
    float* __restrict__ out) {
    int blk = blockIdx.x;
    int b = blk >> 5;
    int i0 = b * 128 + (blk & 31) * 4;
    int tid = threadIdx.x;
    int wr = tid >> 6, lane = tid & 63;
    __shared__ float a[4][NL];
    __shared__ float c0s[4];
    __shared__ float comb[4][48];
    __shared__ float invs[4];

    {
        const float* p1 = P + (size_t)(i0 + wr) * NP + C_P1 + lane * 8;
        const float* p2 = P + (size_t)(i0 + wr) * NP + C_P2 + lane * 8;
        float4 x0 = *(const float4*)(p1);
        float4 x1 = *(const float4*)(p1 + 4);
        float4 y0 = *(const float4*)(p2);
        float4 y1 = *(const float4*)(p2 + 4);
        float s = x0.x * y0.x + x0.y * y0.y + x0.z * y0.z + x0.w * y0.w
                + x1.x * y1.x + x1.y * y1.y + x1.z * y1.z + x1.w * y1.w;
        for (int off = 32; off; off >>= 1) s += __shfl_down(s, off, 64);
        if (lane == 0) c0s[wr] = s;
    }
    for (int idx = tid; idx < 4 * 45; idx += 256) {
        int r = idx / 45, t = idx - r * 45;
        const float* Prow = P + (size_t)(i0 + r) * NP;
        comb[r][t] = Prow[C_D1 + t] + Prow[C_D2 + t];
    }
    __syncthreads();

#pragma unroll
    for (int k = 0; k < 2; k++) {
        int idx = tid + k * 256;
        int r = idx >> 7, j = idx & 127;
        int tt = dep[(size_t)(i0 + r) * NL + j];
        a[r][j] = (tt != 0) ? expf(c0s[r] + comb[r][tt]) : 0.f;
    }
    __syncthreads();
    {
        float v = a[wr][lane] + a[wr][lane + 64];
        for (int off = 32; off; off >>= 1) v += __shfl_down(v, off, 64);
        if (lane == 0) invs[wr] = 1.0f / (v + 1e-6f);
    }
    __syncthreads();

    int o2 = tid * 2;
    float s00 = 0.f, s01 = 0.f, s10 = 0.f, s11 = 0.f;
    float s20 = 0.f, s21 = 0.f, s30 = 0.f, s31 = 0.f;
    const ushort* hp = HTb + (size_t)b * NL * 512 + o2;
#pragma unroll 8
    for (int j = 0; j < NL; j++) {
        ushort2 hv = *(const ushort2*)(hp + (size_t)j * 512);
        float h0 = bf2f(hv.x), h1 = bf2f(hv.y);
        float a0 = a[0][j], a1 = a[1][j], a2 = a[2][j], a3 = a[3][j];
        s00 += a0 * h0; s01 += a0 * h1;
        s10 += a1 * h0; s11 += a1 * h1;
        s20 += a2 * h0; s21 += a2 * h1;
        s30 += a3 * h0; s31 += a3 * h1;
    }
    float bv0 = bias[o2], bv1 = bias[o2 + 1];
    float i0v = invs[0], i1v = invs[1], i2v = invs[2], i3v = invs[3];
    float2 o;
    o.x = fmaxf(s00 * i0v + bv0, 0.f); o.y = fmaxf(s01 * i0v + bv1, 0.f);
    *(float2*)&out[(size_t)(i0 + 0) * 512 + o2] = o;
    o.x = fmaxf(s10 * i1v + bv0, 0.f); o.y = fmaxf(s11 * i1v + bv1, 0.f);
    *(float2*)&out[(size_t)(i0 + 1) * 512 + o2] = o;
    o.x = fmaxf(s20 * i2v + bv0, 0.f); o.y = fmaxf(s21 * i2v + bv1, 0.f);
    *(float2*)&out[(size_t)(i0 + 2) * 512 + o2] = o;
    o.x = fmaxf(s30 * i3v + bv0, 0.f); o.y = fmaxf(s31 * i3v + bv1, 0.f);
    *(float2*)&out[(size_t)(i0 + 3) * 512 + o2] = o;
}

extern "C" void kernel_launch(void* const* d_in, const int* in_sizes, int n_in,
                              void* d_out, int out_size, void* d_ws, size_t ws_size,
                              hipStream_t stream) {
    const float* h    = (const float*)d_in[0];
    const int* dep    = (const int*)d_in[1];
    const unsigned char* mask = (const unsigned char*)d_in[2];
    const float* emb  = (const float*)d_in[3];
    const float* W1   = (const float*)d_in[4];
    const float* b1   = (const float*)d_in[5];
    const float* W2   = (const float*)d_in[6];
    const float* b2   = (const float*)d_in[7];
    const float* Wg   = (const float*)d_in[8];
    const float* bg   = (const float*)d_in[9];
    const float* bias = (const float*)d_in[10];
    float* out = (float*)d_out;

    char* p = (char*)d_ws;
    ushort* A_hi = (ushort*)p;  p += (size_t)1024 * 512 * 2;   // 1 MB
    ushort* A_lo = (ushort*)p;  p += (size_t)1024 * 512 * 2;
    ushort* B_hi = (ushort*)p;  p += (size_t)NP * 512 * 2;     // 1.7 MB
    ushort* B_lo = (ushort*)p;  p += (size_t)NP * 512 * 2;
    ushort* HTb = (ushort*)p;   p += (size_t)1024 * 512 * 2;   // 1 MB
    float* bias_ext = (float*)p; p += NP * 4;
    float* Pout = (float*)p;    // 1024*1664*4 (HT region unused)

    k_prep<<<324, 256, 0, stream>>>(h, mask, emb, W1, W2, Wg, b1, b2, bg,
                                    A_hi, A_lo, B_hi, B_lo, bias_ext);
    dim3 g3(16, 26);
    k3_gemm<<<g3, 256, 0, stream>>>(A_hi, A_lo, B_hi, B_lo, bias_ext, Pout, HTb);
    k5_out<<<256, 256, 0, stream>>>(Pout, dep, HTb, bias, out);
}